// Round 7
// baseline (1102.122 us; speedup 1.0000x reference)
//
#include <hip/hip_runtime.h>
#include <float.h>
#include <math.h>

// DGCNN control-points pipeline, fp32 compute; MFMA (f16 hi/lo split) for the
// knn Gram matrix, edge-conv projection, and f16-MFMA for the layer-5 GEMM.
//
// Edge conv decomposition: y[b,o,n,k] = W·[nbr-ctr; ctr]
//   = v[b, idx(n,k), o] + u[b,n,o]   with v = Wd·x, u = (Wc-Wd)·x
// BN is batch-stats. Single gather pass records per-(b,n,o) ymax/ymin and
// accumulates per-channel sum/sumsq; BN+lrelu+k-max applied elementwise.
// knn: G = X^T X via mfma_f32_16x16x32_f16 with x = hi+lo f16 split;
// d = x2[n]+x2[m]-2G; per-wave register top-20 (exact lax.top_k order).
// Layer-5 (2048x963x8192) on matrix cores, BN-stat/max fused via atomics.
//
// R1: k_gather o-chunked + XCD-affinity (blockIdx%8), nontemporal streams.
// R2: global_load_lds single-buffered -> regressed (exposed L2 latency).
// R3: 2-phase dbuf pipeline w/ __syncthreads: l5 95->80us.
// R4: counted-vmcnt raw-barrier pipeline (T3+T4). l5 ~77us (structure
//     ceiling for this shape; m102 curve).
// R5: k_vu -> MFMA (k_vu_mfma). Total 1065->1001us.
// R6: G is symmetric: k_gram computes only the 136 upper-triangular tiles
//     (of 256) per batch and mirrors off-diagonal tiles on write. Mirror
//     element = same product set, hl/lh sum order swapped (+-1ulp, far
//     under the f16-split 2^-22 noise). Gram aggregate ~112 -> ~62us est.

#define NPTS 2048
#define BATCH 4
#define KNN 20
#define CH_H 963
#define KPAD 992              // 963 padded to 31*32
#define HSTRIDE (CH_H*NPTS)   // per-batch element stride of concat buffer H

typedef _Float16 half8 __attribute__((ext_vector_type(8)));
typedef float f32x4 __attribute__((ext_vector_type(4)));

// direct global->LDS 16B DMA; lds dest is wave-uniform base + lane*16
typedef const __attribute__((address_space(1))) unsigned int* gas_p;
typedef __attribute__((address_space(3))) unsigned int* las_p;
__device__ __forceinline__ void gl_lds16(const void* g, void* l){
  __builtin_amdgcn_global_load_lds((gas_p)g, (las_p)l, 16, 0, 0);
}

// order-preserving float<->uint for atomicMax/Min
__device__ __forceinline__ unsigned fenc(float x){
  unsigned u = __float_as_uint(x);
  return (u & 0x80000000u) ? ~u : (u | 0x80000000u);
}
__device__ __forceinline__ float fdec(unsigned u){
  u = (u & 0x80000000u) ? (u ^ 0x80000000u) : ~u;
  return __uint_as_float(u);
}

// ---------------- copy input x (B,3,N) -> H rows [0,3) ----------------
__global__ void k_convert(const float* __restrict__ x, float* __restrict__ H){
  int i = blockIdx.x*256 + threadIdx.x;
  if (i >= BATCH*3*NPTS) return;
  int b = i / (3*NPTS); int r = i % (3*NPTS);
  H[(size_t)b*HSTRIDE + r] = x[i];
}

// ---------------- per-point squared norms (+ zero SUM/SUMSQ for this layer) ----------------
__global__ void k_norms(const float* __restrict__ X, int C, float* __restrict__ X2,
                        float* __restrict__ SUMZ){
  int i = blockIdx.x*256 + threadIdx.x;     // b*2048+n
  if (i < 1024) SUMZ[i] = 0.f;              // SUM[512] ++ SUMSQ[512] contiguous
  int b = i >> 11, n = i & 2047;
  const float* Xb = X + (size_t)b*HSTRIDE + n;
  float s = 0.f;
  for (int c=0;c<C;++c){ float v = Xb[(size_t)c*NPTS]; s = fmaf(v,v,s); }
  X2[i] = s;
}

// ---------------- X (b,c,n) fp32 -> Xhi/Xlo (b,n,Cpad) f16 split ----------------
__global__ __launch_bounds__(256) void k_xsplit(const float* __restrict__ X, int C, int Cpad,
        _Float16* __restrict__ Xhi, _Float16* __restrict__ Xlo)
{
  __shared__ float t[64][65];
  int b = blockIdx.z;
  int n0 = blockIdx.x*64, c0 = blockIdx.y*64;
  int tid = threadIdx.x; int l = tid & 63, m = tid >> 6;
  for (int cc = m; cc < 64; cc += 4){
    int c = c0 + cc;
    t[cc][l] = (c < C) ? X[(size_t)b*HSTRIDE + (size_t)c*NPTS + n0 + l] : 0.f;
  }
  __syncthreads();
  for (int nn = m; nn < 64; nn += 4){
    int c = c0 + l;
    if (c < Cpad){
      float v = t[l][nn];
      _Float16 h = (_Float16)v;
      size_t o = ((size_t)(b<<11)+n0+nn)*Cpad + c;
      Xhi[o] = h;
      Xlo[o] = (_Float16)(v - (float)h);
    }
  }
}

// ---------------- W (O,2C) fp32 -> Wcat=[Wd; Wc-Wd] (2O,Cpad) f16 hi/lo ----------------
__global__ void k_wsplit(const float* __restrict__ W, int C, int Cpad, int O,
        _Float16* __restrict__ Wh, _Float16* __restrict__ Wl){
  int i = blockIdx.x*256 + threadIdx.x;
  if (i >= 2*O*Cpad) return;
  int op = i / Cpad, c = i - op*Cpad;
  float v = 0.f;
  if (c < C){
    const float* wr = W + (size_t)(op < O ? op : op - O)*(2*C);
    v = (op < O) ? wr[c] : (wr[C+c] - wr[c]);
  }
  _Float16 h = (_Float16)v;
  Wh[i] = h; Wl[i] = (_Float16)(v - (float)h);
}

// ---------------- Gram via MFMA: G[n][m] = sum_c X[n][c]*X[m][c] ----------------
// 128x128 tile, 4 waves x (64x64); 3 MFMAs (hh,hl,lh) per fragment pair.
// R4: counted-vmcnt raw-barrier pipeline, depth-2 prefetch.
// R6: triangular tile enumeration (blockIdx.x = t in [0,136)), mirror
//     off-diagonal tiles on write (G symmetric).
__global__ __launch_bounds__(256) void k_gram(const _Float16* __restrict__ Xhi,
        const _Float16* __restrict__ Xlo, int Cpad, int bbase,
        float* __restrict__ G0, float* __restrict__ G1)
{
  __shared__ half8 AsH[2][128][4]; __shared__ half8 AsL[2][128][4];
  __shared__ half8 BsH[2][128][4]; __shared__ half8 BsL[2][128][4];
  int bl = blockIdx.z;
  int b  = bbase + bl;
  float* G = bl ? G1 : G0;
  const _Float16* Hb = Xhi + (size_t)(b<<11)*Cpad;
  const _Float16* Lb = Xlo + (size_t)(b<<11)*Cpad;
  // triangular decode: t -> (i,j), i<=j over 16x16 tile grid
  int t = blockIdx.x;
  int i = 0, rem = t;
  while (rem >= 16 - i){ rem -= 16 - i; ++i; }
  int j = i + rem;
  int n0 = i*128, m0 = j*128;
  int tid = threadIdx.x;
  int w = tid>>6, lane = tid&63;
  int wm = w>>1, wn = w&1;
  int quad = lane>>4, col = lane&15;
  int wbase = w*128;                    // staging slice base (in cid units)
  f32x4 acc[4][4];
  #pragma unroll
  for (int a=0;a<4;++a)
    #pragma unroll
    for (int c2=0;c2<4;++c2) acc[a][c2] = (f32x4){0.f,0.f,0.f,0.f};

  auto stageg = [&](int buf, int k0){
    #pragma unroll
    for (int s=0;s<2;++s){
      int cid = wbase + s*64 + lane;
      int row = cid>>2, kc = cid&3;
      size_t ao = (size_t)(n0+row)*Cpad + k0 + kc*8;
      size_t bo = (size_t)(m0+row)*Cpad + k0 + kc*8;
      int lo = (wbase + s*64)*16;       // wave-uniform LDS byte base
      gl_lds16(Hb + ao, (char*)&AsH[buf][0][0] + lo);
      gl_lds16(Lb + ao, (char*)&AsL[buf][0][0] + lo);
      gl_lds16(Hb + bo, (char*)&BsH[buf][0][0] + lo);
      gl_lds16(Lb + bo, (char*)&BsL[buf][0][0] + lo);
    }
  };

  int NT = Cpad >> 5;
  stageg(0, 0);                         // 8 loads in flight
  if (NT > 1) stageg(1, 32);            // 16 in flight
  for (int kt=0; kt<NT; ++kt){
    int buf = kt & 1;
    // wait only THIS buf's 8 loads; next buf's 8 stay in flight (T4)
    if (kt+1 < NT) asm volatile("s_waitcnt vmcnt(8)" ::: "memory");
    else           asm volatile("s_waitcnt vmcnt(0)" ::: "memory");
    __builtin_amdgcn_s_barrier();       // RAW: all waves' loads landed
    __builtin_amdgcn_sched_barrier(0);
    half8 ah[4], al[4], bh[4], blo[4];
    #pragma unroll
    for (int mt=0;mt<4;++mt){ ah[mt] = AsH[buf][wm*64 + mt*16 + col][quad];
                              al[mt] = AsL[buf][wm*64 + mt*16 + col][quad]; }
    #pragma unroll
    for (int nt=0;nt<4;++nt){ bh[nt] = BsH[buf][wn*64 + nt*16 + col][quad];
                              blo[nt] = BsL[buf][wn*64 + nt*16 + col][quad]; }
    #pragma unroll
    for (int mt=0;mt<4;++mt)
      #pragma unroll
      for (int nt=0;nt<4;++nt){
        acc[mt][nt] = __builtin_amdgcn_mfma_f32_16x16x32_f16(ah[mt], bh[nt], acc[mt][nt], 0, 0, 0);
        acc[mt][nt] = __builtin_amdgcn_mfma_f32_16x16x32_f16(ah[mt], blo[nt], acc[mt][nt], 0, 0, 0);
        acc[mt][nt] = __builtin_amdgcn_mfma_f32_16x16x32_f16(al[mt], bh[nt], acc[mt][nt], 0, 0, 0);
      }
    __builtin_amdgcn_sched_barrier(0);
    __builtin_amdgcn_s_barrier();       // WAR: all waves done reading buf
    if (kt+2 < NT) stageg(buf, (kt+2)<<5);  // overwrite buf for tile kt+2
  }
  // C/D layout: col(m within 16)=lane&15, row(n within 16)=quad*4+r
  bool mirror = (i != j);
  #pragma unroll
  for (int mt=0;mt<4;++mt){
    #pragma unroll
    for (int r=0;r<4;++r){
      int n = n0 + wm*64 + mt*16 + quad*4 + r;
      #pragma unroll
      for (int nt=0;nt<4;++nt){
        int m = m0 + wn*64 + nt*16 + col;
        float y = acc[mt][nt][r];
        G[(size_t)n*2048 + m] = y;
        if (mirror) G[(size_t)m*2048 + n] = y;
      }
    }
  }
}

// ---------------- edge-conv projection on MFMA: Y(n,o') = X(n,:)·Wcat(o',:) ----------------
// o' in [0,2O): rows [0,O)=Wd -> V, rows [O,2O)=Wc-Wd -> U.
// Same 128x128 tile + counted-vmcnt pipeline as k_gram (R5).
__global__ __launch_bounds__(256) void k_vu_mfma(const _Float16* __restrict__ Xh,
        const _Float16* __restrict__ Xl, const _Float16* __restrict__ Wh,
        const _Float16* __restrict__ Wl, int Cpad, int O,
        float* __restrict__ V, float* __restrict__ U)
{
  __shared__ half8 AsH[2][128][4]; __shared__ half8 AsL[2][128][4];
  __shared__ half8 BsH[2][128][4]; __shared__ half8 BsL[2][128][4];
  int b = blockIdx.z;
  const _Float16* Hb = Xh + (size_t)(b<<11)*Cpad;
  const _Float16* Lb = Xl + (size_t)(b<<11)*Cpad;
  int n0 = blockIdx.x*128, o0 = blockIdx.y*128;   // o0 in o' space
  int tid = threadIdx.x;
  int w = tid>>6, lane = tid&63;
  int wm = w>>1, wn = w&1;
  int quad = lane>>4, col = lane&15;
  int wbase = w*128;
  f32x4 acc[4][4];
  #pragma unroll
  for (int i=0;i<4;++i)
    #pragma unroll
    for (int j=0;j<4;++j) acc[i][j] = (f32x4){0.f,0.f,0.f,0.f};

  auto stagev = [&](int buf, int k0){
    #pragma unroll
    for (int i=0;i<2;++i){
      int cid = wbase + i*64 + lane;
      int row = cid>>2, kc = cid&3;
      size_t ao = (size_t)(n0+row)*Cpad + k0 + kc*8;
      size_t bo = (size_t)(o0+row)*Cpad + k0 + kc*8;
      int lo = (wbase + i*64)*16;
      gl_lds16(Hb + ao, (char*)&AsH[buf][0][0] + lo);
      gl_lds16(Lb + ao, (char*)&AsL[buf][0][0] + lo);
      gl_lds16(Wh + bo, (char*)&BsH[buf][0][0] + lo);
      gl_lds16(Wl + bo, (char*)&BsL[buf][0][0] + lo);
    }
  };

  int NT = Cpad >> 5;
  stagev(0, 0);
  if (NT > 1) stagev(1, 32);
  for (int kt=0; kt<NT; ++kt){
    int buf = kt & 1;
    if (kt+1 < NT) asm volatile("s_waitcnt vmcnt(8)" ::: "memory");
    else           asm volatile("s_waitcnt vmcnt(0)" ::: "memory");
    __builtin_amdgcn_s_barrier();
    __builtin_amdgcn_sched_barrier(0);
    half8 ah[4], al[4], bh[4], blo[4];
    #pragma unroll
    for (int mt=0;mt<4;++mt){ ah[mt] = AsH[buf][wm*64 + mt*16 + col][quad];
                              al[mt] = AsL[buf][wm*64 + mt*16 + col][quad]; }
    #pragma unroll
    for (int nt=0;nt<4;++nt){ bh[nt] = BsH[buf][wn*64 + nt*16 + col][quad];
                              blo[nt] = BsL[buf][wn*64 + nt*16 + col][quad]; }
    #pragma unroll
    for (int mt=0;mt<4;++mt)
      #pragma unroll
      for (int nt=0;nt<4;++nt){
        acc[mt][nt] = __builtin_amdgcn_mfma_f32_16x16x32_f16(ah[mt], bh[nt], acc[mt][nt], 0, 0, 0);
        acc[mt][nt] = __builtin_amdgcn_mfma_f32_16x16x32_f16(ah[mt], blo[nt], acc[mt][nt], 0, 0, 0);
        acc[mt][nt] = __builtin_amdgcn_mfma_f32_16x16x32_f16(al[mt], bh[nt], acc[mt][nt], 0, 0, 0);
      }
    __builtin_amdgcn_sched_barrier(0);
    __builtin_amdgcn_s_barrier();
    if (kt+2 < NT) stagev(buf, (kt+2)<<5);
  }
  // epilogue: (n, o') -> V if o'<O else U
  #pragma unroll
  for (int mt=0;mt<4;++mt){
    #pragma unroll
    for (int r=0;r<4;++r){
      int n = n0 + wm*64 + mt*16 + quad*4 + r;
      size_t R = (size_t)(b<<11) + n;
      #pragma unroll
      for (int nt=0;nt<4;++nt){
        int op = o0 + wn*64 + nt*16 + col;
        float y = acc[mt][nt][r];
        if (op < O) V[R*O + op] = y;
        else        U[R*O + op - O] = y;
      }
    }
  }
}

// ---------------- top-20 selection from Gram row ----------------
// 32 register slots per lane: slot (ch,cp) <-> candidate m = ch*256 + (lane<<2) + cp
#define KNN_CH(OPC) OPC(0) OPC(1) OPC(2) OPC(3) OPC(4) OPC(5) OPC(6) OPC(7)
#define DECL_CH(ch) float d##ch##_0,d##ch##_1,d##ch##_2,d##ch##_3;
#define LOADG_CH(ch) { float4 g = *(const float4*)(grow + (ch)*256 + base); \
  float4 xm = *(const float4*)(x2b + (ch)*256 + base); \
  d##ch##_0 = x2n + xm.x - 2.f*g.x; d##ch##_1 = x2n + xm.y - 2.f*g.y; \
  d##ch##_2 = x2n + xm.z - 2.f*g.z; d##ch##_3 = x2n + xm.w - 2.f*g.w; }
#define DECL_G(ch) float gv##ch; int gm##ch;
// strict < in ascending slot order -> smallest idx among exact ties
#define MKCH(ch) { gv##ch = d##ch##_0; gm##ch = (ch)*256 + base; \
  if (d##ch##_1 < gv##ch){ gv##ch = d##ch##_1; gm##ch = (ch)*256 + base + 1; } \
  if (d##ch##_2 < gv##ch){ gv##ch = d##ch##_2; gm##ch = (ch)*256 + base + 2; } \
  if (d##ch##_3 < gv##ch){ gv##ch = d##ch##_3; gm##ch = (ch)*256 + base + 3; } }
#define REMCASE(ch) case ch: { \
  if (own){ if (cp==0) d##ch##_0 = FLT_MAX; else if (cp==1) d##ch##_1 = FLT_MAX; \
            else if (cp==2) d##ch##_2 = FLT_MAX; else d##ch##_3 = FLT_MAX; } \
  MKCH(ch) } break;

__global__ __launch_bounds__(256,4) void k_sel(const float* __restrict__ G0,
        const float* __restrict__ G1, const float* __restrict__ X2,
        int bbase, int* __restrict__ IDX)
{
  int tid = threadIdx.x;
  int w = tid >> 6, lane = tid & 63;
  int n = blockIdx.x*4 + w;
  int b = bbase + blockIdx.y;
  const float* grow = (blockIdx.y ? G1 : G0) + (size_t)n*2048;
  const float* x2b  = X2 + (b<<11);
  float x2n = x2b[n];
  int base = lane << 2;
  KNN_CH(DECL_CH)
  KNN_CH(LOADG_CH)
  KNN_CH(DECL_G)
  KNN_CH(MKCH)
  int* op = IDX + ((size_t)(b<<11)+n)*KNN;
  for (int it=0; it<KNN; ++it){
    float v = fminf(fminf(fminf(gv0,gv1),fminf(gv2,gv3)),
                    fminf(fminf(gv4,gv5),fminf(gv6,gv7)));
    #pragma unroll
    for (int s=1; s<64; s<<=1) v = fminf(v, __shfl_xor(v, s));
    int mc = 0x7fffffff;
    mc = (gv7==v) ? gm7 : mc;
    mc = (gv6==v) ? gm6 : mc;
    mc = (gv5==v) ? gm5 : mc;
    mc = (gv4==v) ? gm4 : mc;
    mc = (gv3==v) ? gm3 : mc;
    mc = (gv2==v) ? gm2 : mc;
    mc = (gv1==v) ? gm1 : mc;
    mc = (gv0==v) ? gm0 : mc;
    int m = mc;
    #pragma unroll
    for (int s=1; s<64; s<<=1) m = min(m, __shfl_xor(m, s));
    if (lane==0) op[it] = m;
    int sm = __builtin_amdgcn_readfirstlane(m);
    bool own = (lane == ((sm>>2)&63));
    int cp = sm & 3;
    switch (sm >> 8){ KNN_CH(REMCASE) }
  }
}

// ---------------- single gather pass: ymax/ymin per (b,n,o) + channel sum/sumsq ----------------
// OC-wide o-chunk per block, XCD-affinity via blockIdx%8 round-robin
// (b = xcd>>1, o-half = xcd&1) -> per-XCD random-read working set of V is
// 2048 x OC x 4B (<= 2MB), L2-resident after compulsory misses.
// U reads / YMX,YMN writes are use-once streams -> nontemporal so they don't
// evict V. U hoisted out of k-loop; per-o LDS reduce before global atomics.
template<int OC, int CHN>
__global__ __launch_bounds__(256) void k_gather(const float* __restrict__ V,
        const float* __restrict__ U, const int* __restrict__ IDX,
        float* __restrict__ YMX, float* __restrict__ YMN,
        float* __restrict__ SUM, float* __restrict__ SUMSQ)
{
  constexpr int O = OC*CHN;
  constexpr int NT = 8;
  constexpr int NSTEP = 256/OC;       // threads sharing one o column
  __shared__ int sidx[NT*KNN];
  __shared__ float rs[256], rq[256];
  int bid = blockIdx.x;
  int xcd  = bid & 7;                 // HW round-robin wg->XCD (learn_hip m09)
  int b    = xcd >> 1;
  int half = xcd & 1;
  int r    = bid >> 3;
  int ngrp, chunk;
  if (CHN == 1){ ngrp = (half<<7) | r; chunk = 0; }        // r in [0,128)
  else         { ngrp = r & 255; chunk = half*(CHN/2) + (r>>8); }
  int n0 = ngrp * NT;
  int tid = threadIdx.x;
  for (int l = tid; l < NT*KNN; l += 256)
    sidx[l] = IDX[((size_t)(b<<11)+n0)*KNN + l];
  __syncthreads();
  int o  = chunk*OC + (tid & (OC-1));
  int ns = tid / OC;
  const float* Vb = V + (size_t)(b<<11)*O + o;
  float s = 0.f, q = 0.f;
  #pragma unroll
  for (int i = 0; i < NT/NSTEP; ++i){
    int nn = ns + i*NSTEP;
    int n = n0 + nn;
    size_t ub = ((size_t)(b<<11)+n)*O + o;
    float sv = 0.f, sv2 = 0.f, mx = -FLT_MAX, mn = FLT_MAX;
    #pragma unroll
    for (int k=0;k<KNN;++k){
      int m = sidx[nn*KNN+k];
      float v = Vb[(size_t)m*O];
      mx = fmaxf(mx,v); mn = fminf(mn,v);
      sv += v; sv2 = fmaf(v,v,sv2);
    }
    float u = __builtin_nontemporal_load(U + ub);
    __builtin_nontemporal_store(mx + u, YMX + ub);
    __builtin_nontemporal_store(mn + u, YMN + ub);
    s += sv + (float)KNN * u;
    q += sv2 + 2.f*u*sv + (float)KNN*u*u;
  }
  rs[tid] = s; rq[tid] = q;
  __syncthreads();
  if (tid < OC){
    #pragma unroll
    for (int t=1; t<NSTEP; ++t){ s += rs[tid + t*OC]; q += rq[tid + t*OC]; }
    atomicAdd(&SUM[o], s);
    atomicAdd(&SUMSQ[o], q);
  }
}

__global__ void k_finalize(const float* __restrict__ SUM, const float* __restrict__ SUMSQ,
        const float* __restrict__ g, const float* __restrict__ bt,
        int O, float invM, float* __restrict__ SC, float* __restrict__ SH){
  int o = blockIdx.x*256 + threadIdx.x;
  if (o>=O) return;
  float m = SUM[o]*invM;
  float var = SUMSQ[o]*invM - m*m;
  float sc = g[o] * rsqrtf(var + 1e-5f);
  SC[o]=sc; SH[o] = bt[o] - m*sc;
}

// ---------------- apply BN + lrelu to recorded extrema; transpose (b,n,o)->(b,o,n) ----------------
__global__ __launch_bounds__(256) void k_apply(const float* __restrict__ YMX, const float* __restrict__ YMN,
        const float* __restrict__ SC, const float* __restrict__ SH,
        int O, float* __restrict__ OUT)
{
  __shared__ float t[64][65];
  int b = blockIdx.z;
  int o0 = blockIdx.y*64, n0 = blockIdx.x*64;
  int tid = threadIdx.x;
  int lo = tid & 63, ln = tid >> 6;
  float sc = SC[o0+lo], sh = SH[o0+lo];
  for (int nn = ln; nn < 64; nn += 4){
    size_t idx = ((size_t)(b<<11)+n0+nn)*O + o0 + lo;
    float v = (sc >= 0.f) ? YMX[idx] : YMN[idx];
    float y = fmaf(sc, v, sh);
    y = (y > 0.f) ? y : 0.2f*y;
    t[lo][nn] = y;
  }
  __syncthreads();
  for (int oo = ln; oo < 64; oo += 4){
    OUT[(size_t)b*HSTRIDE + (size_t)(o0+oo)*NPTS + n0 + lo] = t[oo][lo];
  }
}

// ---------------- transpose H (b,c,n) fp32 -> Hf16 (b,n,KPAD) f16, zero-pad c>=963 ----------------
__global__ __launch_bounds__(256) void k_h2f16(const float* __restrict__ H, _Float16* __restrict__ Hf){
  __shared__ float t[64][65];
  int b = blockIdx.z;
  int n0 = blockIdx.x*64, c0 = blockIdx.y*64;
  int tid = threadIdx.x; int l = tid & 63, m = tid >> 6;
  for (int cc = m; cc < 64; cc += 4){
    int c = c0 + cc;
    t[cc][l] = (c < CH_H) ? H[(size_t)b*HSTRIDE + (size_t)c*NPTS + n0 + l] : 0.f;
  }
  __syncthreads();
  for (int nn = m; nn < 64; nn += 4){
    int c = c0 + l;
    if (c < KPAD)
      Hf[((size_t)(b<<11)+n0+nn)*KPAD + c] = (_Float16)t[l][nn];
  }
}

// ---------------- w5 -> f16 (+ zero l5 reduction buffers) ----------------
__global__ void k_w5f16(const float* __restrict__ w5, _Float16* __restrict__ Wf,
                        unsigned* __restrict__ z){
  int i = blockIdx.x*256 + threadIdx.x;
  if (i < 12288) z[i] = 0u;                 // SUM5,SUMSQ5,MAXB
  else if (i < 20480) z[i] = 0xFFFFFFFFu;   // MINB
  if (i >= 2048*KPAD) return;
  int o = i / KPAD, c = i - o*KPAD;
  Wf[i] = (c < CH_H) ? (_Float16)w5[(size_t)o*CH_H + c] : (_Float16)0.f;
}

// ---------------- layer-5 GEMM on MFMA, fused BN-stat/max epilogue ----------------
// R4: counted-vmcnt raw-barrier pipeline, depth-2 prefetch (4 loads/wave/stage).
__global__ __launch_bounds__(256) void k_l5mfma(const _Float16* __restrict__ Wf,
        const _Float16* __restrict__ Hf,
        float* __restrict__ SUM5, float* __restrict__ SUMSQ5,
        unsigned* __restrict__ MAXB, unsigned* __restrict__ MINB)
{
  __shared__ half8 As[2][128][4];   // [buf][o_row][k-chunk of 8]
  __shared__ half8 Bs[2][128][4];   // [buf][n_row][k-chunk of 8]
  int b  = blockIdx.z;
  int n0 = blockIdx.x*128, o0 = blockIdx.y*128;
  int tid = threadIdx.x;
  int w = tid>>6, lane = tid&63;
  int wm = w>>1, wn = w&1;          // wave grid 2x2
  int quad = lane>>4, col = lane&15;
  int wbase = w*128;                // staging slice base (in cid units)
  f32x4 acc[4][4];
  #pragma unroll
  for (int i=0;i<4;++i)
    #pragma unroll
    for (int j=0;j<4;++j) acc[i][j] = (f32x4){0.f,0.f,0.f,0.f};

  auto stage5 = [&](int buf, int k0){
    #pragma unroll
    for (int i=0;i<2;++i){
      int cid = wbase + i*64 + lane;
      int row = cid>>2, kc = cid&3;
      int lo = (wbase + i*64)*16;   // wave-uniform LDS byte base
      gl_lds16(Wf + (size_t)(o0+row)*KPAD + k0 + kc*8, (char*)&As[buf][0][0] + lo);
      gl_lds16(Hf + ((size_t)(b<<11)+n0+row)*KPAD + k0 + kc*8, (char*)&Bs[buf][0][0] + lo);
    }
  };

  const int NT = KPAD/32;           // 31
  stage5(0, 0);                     // 4 loads in flight
  stage5(1, 32);                    // 8 in flight
  for (int kt=0; kt<NT; ++kt){
    int buf = kt & 1;
    // wait only THIS buf's 4 loads; next buf's 4 stay in flight (T4)
    if (kt+1 < NT) asm volatile("s_waitcnt vmcnt(4)" ::: "memory");
    else           asm volatile("s_waitcnt vmcnt(0)" ::: "memory");
    __builtin_amdgcn_s_barrier();   // RAW: all waves' loads landed
    __builtin_amdgcn_sched_barrier(0);
    half8 af[4], bf[4];
    #pragma unroll
    for (int mt=0;mt<4;++mt) af[mt] = As[buf][wm*64 + mt*16 + col][quad];
    #pragma unroll
    for (int nt=0;nt<4;++nt) bf[nt] = Bs[buf][wn*64 + nt*16 + col][quad];
    #pragma unroll
    for (int mt=0;mt<4;++mt)
      #pragma unroll
      for (int nt=0;nt<4;++nt)
        acc[mt][nt] = __builtin_amdgcn_mfma_f32_16x16x32_f16(af[mt], bf[nt], acc[mt][nt], 0, 0, 0);
    __builtin_amdgcn_sched_barrier(0);
    __builtin_amdgcn_s_barrier();   // WAR: all waves done reading buf
    if (kt+2 < NT) stage5(buf, (kt+2)*32);  // overwrite buf for tile kt+2
  }
  // epilogue: C/D layout col(n)=lane&15, row(o)=quad*4+reg
  #pragma unroll
  for (int mt=0;mt<4;++mt){
    #pragma unroll
    for (int r=0;r<4;++r){
      float s=0.f, q=0.f, mx=-FLT_MAX, mn=FLT_MAX;
      #pragma unroll
      for (int nt=0;nt<4;++nt){
        float y = acc[mt][nt][r];
        s += y; q = fmaf(y,y,q);
        mx = fmaxf(mx,y); mn = fminf(mn,y);
      }
      #pragma unroll
      for (int d=8; d; d>>=1){
        s += __shfl_down(s,(unsigned)d,16);
        q += __shfl_down(q,(unsigned)d,16);
        mx = fmaxf(mx,__shfl_down(mx,(unsigned)d,16));
        mn = fminf(mn,__shfl_down(mn,(unsigned)d,16));
      }
      if (col==0){
        int o = o0 + wm*64 + mt*16 + quad*4 + r;
        atomicAdd(&SUM5[o], s);
        atomicAdd(&SUMSQ5[o], q);
        atomicMax(&MAXB[(b<<11)+o], fenc(mx));
        atomicMin(&MINB[(b<<11)+o], fenc(mn));
      }
    }
  }
}

// ---------------- layer-5 finalize: BN + leaky_relu + max over n -> P (B,2048) ----------------
__global__ void k_l5_final(const float* __restrict__ SUM5, const float* __restrict__ SUMSQ5,
        const unsigned* __restrict__ MAXB, const unsigned* __restrict__ MINB,
        const float* __restrict__ g5, const float* __restrict__ b5, float* __restrict__ P)
{
  int o = blockIdx.x*256 + threadIdx.x;
  if (o>=2048) return;
  float m = SUM5[o]*(1.f/8192.f);
  float var = SUMSQ5[o]*(1.f/8192.f) - m*m;
  float sc = g5[o] * rsqrtf(var + 1e-5f);
  float sh = b5[o] - m*sc;
  for (int b=0;b<4;++b){
    float mx = fdec(MAXB[b*2048+o]);
    float mn = fdec(MINB[b*2048+o]);
    float v = (sc >= 0.f) ? fmaf(sc,mx,sh) : fmaf(sc,mn,sh);
    v = (v > 0.f) ? v : 0.2f*v;
    P[b*2048 + o] = v;
  }
}

// ---------------- small FC: Y(B,O) = W(O,Cin)*Z(B,Cin) + bias, one wave per o ----------------
__global__ __launch_bounds__(256) void k_fc(const float* __restrict__ W, const float* __restrict__ bias,
        const float* __restrict__ Z, int Cin, int O, float* __restrict__ Y)
{
  int o = blockIdx.x*4 + (threadIdx.x>>6);
  int lane = threadIdx.x & 63;
  if (o >= O) return;
  const float* wr = W + (size_t)o*Cin;
  float a0=0.f,a1=0.f,a2=0.f,a3=0.f;
  for (int c=lane;c<Cin;c+=64){
    float w = wr[c];
    a0 = fmaf(w, Z[c],        a0);
    a1 = fmaf(w, Z[Cin+c],    a1);
    a2 = fmaf(w, Z[2*Cin+c],  a2);
    a3 = fmaf(w, Z[3*Cin+c],  a3);
  }
  #pragma unroll
  for (int s=32;s;s>>=1){
    a0 += __shfl_down(a0,(unsigned)s); a1 += __shfl_down(a1,(unsigned)s);
    a2 += __shfl_down(a2,(unsigned)s); a3 += __shfl_down(a3,(unsigned)s);
  }
  if (lane==0){
    float bb = bias[o];
    Y[o]=a0+bb; Y[O+o]=a1+bb; Y[2*O+o]=a2+bb; Y[3*O+o]=a3+bb;
  }
}

// ---------------- BN over batch (4 samples) + relu ----------------
__global__ void k_bn4(const float* __restrict__ Y, const float* __restrict__ g, const float* __restrict__ bt,
                      int O, float* __restrict__ Z, int zstride, int zoff)
{
  int o = blockIdx.x*256 + threadIdx.x;
  if (o>=O) return;
  float v0=Y[o], v1=Y[O+o], v2=Y[2*O+o], v3=Y[3*O+o];
  float m = 0.25f*(v0+v1+v2+v3);
  float d0=v0-m, d1=v1-m, d2=v2-m, d3=v3-m;
  float var = 0.25f*(d0*d0+d1*d1+d2*d2+d3*d3);
  float sc = g[o] * rsqrtf(var + 1e-5f);
  float sh = bt[o] - m*sc;
  Z[0*zstride+zoff+o] = fmaxf(fmaf(sc,v0,sh), 0.f);
  Z[1*zstride+zoff+o] = fmaxf(fmaf(sc,v1,sh), 0.f);
  Z[2*zstride+zoff+o] = fmaxf(fmaf(sc,v2,sh), 0.f);
  Z[3*zstride+zoff+o] = fmaxf(fmaf(sc,v3,sh), 0.f);
}

__global__ void k_copy_p(const float* __restrict__ P, float* __restrict__ Z){
  int i = blockIdx.x*256 + threadIdx.x;   // < 4*2048
  int b = i>>11, o = i&2047;
  Z[b*4096 + 2048 + o] = P[i];
}

// ---------------- final: y8 = w8*z7 + wb8, tanh, fp32 out (4,400) ----------------
__global__ __launch_bounds__(256) void k_final(const float* __restrict__ W8, const float* __restrict__ wb8,
        const float* __restrict__ Z7, float* __restrict__ out)
{
  int o = blockIdx.x*4 + (threadIdx.x>>6);
  int lane = threadIdx.x & 63;
  if (o >= 400) return;
  const float* wr = W8 + (size_t)o*4096;
  float a0=0.f,a1=0.f,a2=0.f,a3=0.f;
  for (int c=lane;c<4096;c+=64){
    float w = wr[c];
    a0 = fmaf(w, Z7[c],        a0);
    a1 = fmaf(w, Z7[4096+c],   a1);
    a2 = fmaf(w, Z7[2*4096+c], a2);
    a3 = fmaf(w, Z7[3*4096+c], a3);
  }
  #pragma unroll
  for (int s=32;s;s>>=1){
    a0 += __shfl_down(a0,(unsigned)s); a1 += __shfl_down(a1,(unsigned)s);
    a2 += __shfl_down(a2,(unsigned)s); a3 += __shfl_down(a3,(unsigned)s);
  }
  if (lane==0){
    float bb = wb8[o];
    out[0*400+o] = tanhf(a0+bb);
    out[1*400+o] = tanhf(a1+bb);
    out[2*400+o] = tanhf(a2+bb);
    out[3*400+o] = tanhf(a3+bb);
  }
}

extern "C" void kernel_launch(void* const* d_in, const int* in_sizes, int n_in,
                              void* d_out, int out_size, void* d_ws, size_t ws_size,
                              hipStream_t stream)
{
  const float* x   = (const float*)d_in[0];
  const float* w_e[4]  = {(const float*)d_in[1], (const float*)d_in[4], (const float*)d_in[7], (const float*)d_in[10]};
  const float* g_e[4]  = {(const float*)d_in[2], (const float*)d_in[5], (const float*)d_in[8], (const float*)d_in[11]};
  const float* b_e[4]  = {(const float*)d_in[3], (const float*)d_in[6], (const float*)d_in[9], (const float*)d_in[12]};
  const float* w5  = (const float*)d_in[13];
  const float* g5  = (const float*)d_in[14];
  const float* b5  = (const float*)d_in[15];
  const float* w6  = (const float*)d_in[16];
  const float* wb6 = (const float*)d_in[17];
  const float* g6  = (const float*)d_in[18];
  const float* b6  = (const float*)d_in[19];
  const float* w7  = (const float*)d_in[20];
  const float* wb7 = (const float*)d_in[21];
  const float* g7  = (const float*)d_in[22];
  const float* b7  = (const float*)d_in[23];
  const float* w8  = (const float*)d_in[24];
  const float* wb8 = (const float*)d_in[25];

  float* WS = (float*)d_ws;
  float* H    = WS;                          // 7,888,896
  float* V    = WS + 7888896;                // 4,194,304
  float* U    = V  + 4194304;                // 4,194,304
  float* YMX  = U  + 4194304;                // 4,194,304
  float* YMN  = YMX+ 4194304;                // 4,194,304
  int*   IDX  = (int*)(YMN + 4194304);       //   163,840 ints
  float* X2   = (float*)(IDX + 163840);      //     8,192
  float* SUM  = X2 + 8192;                   //       512
  float* SUMSQ= SUM + 512;                   //       512
  float* SC   = SUMSQ + 512;                 //       512
  float* SH   = SC + 512;                    //       512
  float* SUM5 = SH + 512;                    //     2,048
  float* SUMSQ5 = SUM5 + 2048;               //     2,048
  unsigned* MAXB = (unsigned*)(SUMSQ5 + 2048); //   8,192
  unsigned* MINB = MAXB + 8192;              //     8,192
  float* P    = (float*)(MINB + 8192);       //     8,192
  float* Y6   = P + 8192;                    //     8,192
  float* Z    = Y6 + 8192;                   //    16,384
  float* Y7   = Z + 16384;                   //    16,384
  float* Z7   = Y7 + 16384;                  //    16,384
  // aliases (stage-disjoint lifetimes):
  _Float16* Hf  = (_Float16*)V;              // l5 operand, after edge stages
  _Float16* Wf  = (_Float16*)U;              // l5 operand
  // R5: knn/edge split operands live in YMN (dead until k_gather overwrites);
  // Gram G1 lives in V (dead until k_vu_mfma writes it, after k_sel reads).
  _Float16* Xhi  = (_Float16*)YMN;                 // 4 MB
  _Float16* Xlo  = Xhi + (size_t)4*2048*256;       // 4 MB
  _Float16* Wsph = Xlo + (size_t)4*2048*256;       // 0.5 MB (max 1024x256)
  _Float16* Wspl = Wsph + 1024*256;                // 0.5 MB
  float* G0 = YMX;                           // per-batch Gram (16.8 MB each)
  float* G1 = V;

  k_convert<<<96,256,0,stream>>>(x, H);

  const int Cin_[4]  = {3,64,128,256};
  const int Cpad_[4] = {32,64,128,256};
  const int O_[4]    = {64,128,256,512};
  const int ioff_[4] = {0,3,67,195};
  const int ooff_[4] = {3,67,195,451};

  for (int l=0;l<4;++l){
    const float* Xl = H + (size_t)ioff_[l]*NPTS;
    int C = Cin_[l], Cpad = Cpad_[l], O = O_[l];
    k_norms<<<32,256,0,stream>>>(Xl, C, X2, SUM);
    dim3 gxs(32, (Cpad+63)/64, 4);
    k_xsplit<<<gxs,256,0,stream>>>(Xl, C, Cpad, Xhi, Xlo);
    k_wsplit<<<(2*O*Cpad+255)/256,256,0,stream>>>(w_e[l], C, Cpad, O, Wsph, Wspl);
    dim3 ggr(136,1,2);                 // R6: triangular tile set
    k_gram<<<ggr,256,0,stream>>>(Xhi, Xlo, Cpad, 0, G0, G1);
    dim3 gsl(512,2);
    k_sel<<<gsl,256,0,stream>>>(G0, G1, X2, 0, IDX);
    k_gram<<<ggr,256,0,stream>>>(Xhi, Xlo, Cpad, 2, G0, G1);
    k_sel<<<gsl,256,0,stream>>>(G0, G1, X2, 2, IDX);
    dim3 gvm(16, (2*O)/128, 4);
    k_vu_mfma<<<gvm,256,0,stream>>>(Xhi, Xlo, Wsph, Wspl, Cpad, O, V, U);
    if (O == 64)
      k_gather<64,1><<<1024,256,0,stream>>>(V, U, IDX, YMX, YMN, SUM, SUMSQ);
    else if (O == 128)
      k_gather<128,1><<<1024,256,0,stream>>>(V, U, IDX, YMX, YMN, SUM, SUMSQ);
    else if (O == 256)
      k_gather<128,2><<<2048,256,0,stream>>>(V, U, IDX, YMX, YMN, SUM, SUMSQ);
    else
      k_gather<128,4><<<4096,256,0,stream>>>(V, U, IDX, YMX, YMN, SUM, SUMSQ);
    k_finalize<<<2,256,0,stream>>>(SUM, SUMSQ, g_e[l], b_e[l], O, 1.f/163840.f, SC, SH);
    dim3 gap(32, O/64, 4);
    k_apply<<<gap,256,0,stream>>>(YMX, YMN, SC, SH, O, H + (size_t)ooff_[l]*NPTS);
  }

  // ---- layer 5 on MFMA ----
  dim3 gtr(32,16,4);
  k_h2f16<<<gtr,256,0,stream>>>(H, Hf);
  k_w5f16<<<(2048*KPAD+255)/256,256,0,stream>>>(w5, Wf, (unsigned*)SUM5);
  dim3 g5g(16,16,4);
  k_l5mfma<<<g5g,256,0,stream>>>(Wf, Hf, SUM5, SUMSQ5, MAXB, MINB);
  k_l5_final<<<8,256,0,stream>>>(SUM5, SUMSQ5, MAXB, MINB, g5, b5, P);

  k_fc<<<512,256,0,stream>>>(w6, wb6, P, 2048, 2048, Y6);
  k_bn4<<<8,256,0,stream>>>(Y6, g6, b6, 2048, Z, 4096, 0);
  k_copy_p<<<32,256,0,stream>>>(P, Z);
  k_fc<<<1024,256,0,stream>>>(w7, wb7, Z, 4096, 4096, Y7);
  k_bn4<<<16,256,0,stream>>>(Y7, g7, b7, 4096, Z7, 4096, 0);
  k_final<<<100,256,0,stream>>>(w8, wb8, Z7, (float*)d_out);
}

// Round 8
// 1026.019 us; speedup vs baseline: 1.0742x; 1.0742x over previous
//
#include <hip/hip_runtime.h>
#include <float.h>
#include <math.h>

// DGCNN control-points pipeline, fp32 compute; MFMA (f16 hi/lo split) for the
// knn Gram matrix, edge-conv projection, and f16-MFMA for the layer-5 GEMM.
//
// Edge conv decomposition: y[b,o,n,k] = W·[nbr-ctr; ctr]
//   = v[b, idx(n,k), o] + u[b,n,o]   with v = Wd·x, u = (Wc-Wd)·x
// BN is batch-stats. Single gather pass records per-(b,n,o) ymax/ymin and
// accumulates per-channel sum/sumsq; BN+lrelu+k-max applied elementwise.
// knn: G = X^T X via mfma_f32_16x16x32_f16 with x = hi+lo f16 split;
// d = x2[n]+x2[m]-2G; per-wave register top-20 (exact lax.top_k order).
// Layer-5 (2048x963x8192) on matrix cores, BN-stat/max fused via atomics.
//
// R1: k_gather o-chunked + XCD-affinity (blockIdx%8), nontemporal streams.
// R2: global_load_lds single-buffered -> regressed (exposed L2 latency).
// R3: 2-phase dbuf pipeline w/ __syncthreads: l5 95->80us.
// R4: counted-vmcnt raw-barrier pipeline (T3+T4). l5 ~77us.
// R5: k_vu -> MFMA (k_vu_mfma). Total 1065->1001us.
// R6: triangular gram REGRESSED (+~50us real): blocks are barrier-latency
//     bound -> halving block count didn't cut wall time (both ~1 co-resident
//     round at 2 blk/CU), and mirror scatter-stores + 1-blk/CU stall
//     exposure added cost. REVERTED.
// R7: R5 structure + T1 XCD-chunked swizzle on k_gram/k_vu_mfma/k_l5mfma
//     (1D grids, bijective %8==0): each XCD gets contiguous operand-panel
//     chunks so panel re-reads hit its private L2 (l5 FETCH 39MB vs 20MB
//     ideal today).

#define NPTS 2048
#define BATCH 4
#define KNN 20
#define CH_H 963
#define KPAD 992              // 963 padded to 31*32
#define HSTRIDE (CH_H*NPTS)   // per-batch element stride of concat buffer H

typedef _Float16 half8 __attribute__((ext_vector_type(8)));
typedef float f32x4 __attribute__((ext_vector_type(4)));

// direct global->LDS 16B DMA; lds dest is wave-uniform base + lane*16
typedef const __attribute__((address_space(1))) unsigned int* gas_p;
typedef __attribute__((address_space(3))) unsigned int* las_p;
__device__ __forceinline__ void gl_lds16(const void* g, void* l){
  __builtin_amdgcn_global_load_lds((gas_p)g, (las_p)l, 16, 0, 0);
}

// order-preserving float<->uint for atomicMax/Min
__device__ __forceinline__ unsigned fenc(float x){
  unsigned u = __float_as_uint(x);
  return (u & 0x80000000u) ? ~u : (u | 0x80000000u);
}
__device__ __forceinline__ float fdec(unsigned u){
  u = (u & 0x80000000u) ? (u ^ 0x80000000u) : ~u;
  return __uint_as_float(u);
}

// ---------------- copy input x (B,3,N) -> H rows [0,3) ----------------
__global__ void k_convert(const float* __restrict__ x, float* __restrict__ H){
  int i = blockIdx.x*256 + threadIdx.x;
  if (i >= BATCH*3*NPTS) return;
  int b = i / (3*NPTS); int r = i % (3*NPTS);
  H[(size_t)b*HSTRIDE + r] = x[i];
}

// ---------------- per-point squared norms (+ zero SUM/SUMSQ for this layer) ----------------
__global__ void k_norms(const float* __restrict__ X, int C, float* __restrict__ X2,
                        float* __restrict__ SUMZ){
  int i = blockIdx.x*256 + threadIdx.x;     // b*2048+n
  if (i < 1024) SUMZ[i] = 0.f;              // SUM[512] ++ SUMSQ[512] contiguous
  int b = i >> 11, n = i & 2047;
  const float* Xb = X + (size_t)b*HSTRIDE + n;
  float s = 0.f;
  for (int c=0;c<C;++c){ float v = Xb[(size_t)c*NPTS]; s = fmaf(v,v,s); }
  X2[i] = s;
}

// ---------------- X (b,c,n) fp32 -> Xhi/Xlo (b,n,Cpad) f16 split ----------------
__global__ __launch_bounds__(256) void k_xsplit(const float* __restrict__ X, int C, int Cpad,
        _Float16* __restrict__ Xhi, _Float16* __restrict__ Xlo)
{
  __shared__ float t[64][65];
  int b = blockIdx.z;
  int n0 = blockIdx.x*64, c0 = blockIdx.y*64;
  int tid = threadIdx.x; int l = tid & 63, m = tid >> 6;
  for (int cc = m; cc < 64; cc += 4){
    int c = c0 + cc;
    t[cc][l] = (c < C) ? X[(size_t)b*HSTRIDE + (size_t)c*NPTS + n0 + l] : 0.f;
  }
  __syncthreads();
  for (int nn = m; nn < 64; nn += 4){
    int c = c0 + l;
    if (c < Cpad){
      float v = t[l][nn];
      _Float16 h = (_Float16)v;
      size_t o = ((size_t)(b<<11)+n0+nn)*Cpad + c;
      Xhi[o] = h;
      Xlo[o] = (_Float16)(v - (float)h);
    }
  }
}

// ---------------- W (O,2C) fp32 -> Wcat=[Wd; Wc-Wd] (2O,Cpad) f16 hi/lo ----------------
__global__ void k_wsplit(const float* __restrict__ W, int C, int Cpad, int O,
        _Float16* __restrict__ Wh, _Float16* __restrict__ Wl){
  int i = blockIdx.x*256 + threadIdx.x;
  if (i >= 2*O*Cpad) return;
  int op = i / Cpad, c = i - op*Cpad;
  float v = 0.f;
  if (c < C){
    const float* wr = W + (size_t)(op < O ? op : op - O)*(2*C);
    v = (op < O) ? wr[c] : (wr[C+c] - wr[c]);
  }
  _Float16 h = (_Float16)v;
  Wh[i] = h; Wl[i] = (_Float16)(v - (float)h);
}

// ---------------- Gram via MFMA: G[n][m] = sum_c X[n][c]*X[m][c] ----------------
// 128x128 tile, 4 waves x (64x64); 3 MFMAs (hh,hl,lh) per fragment pair.
// Counted-vmcnt raw-barrier pipeline, depth-2 prefetch.
// R7: 1D grid (512) + XCD-chunked decode: id2 = bl*256 + j*16 + i, so each
// XCD p reads 4 n-panels + 16 m-panels of ONE batch (~2.5MB, L2-fits).
__global__ __launch_bounds__(256) void k_gram(const _Float16* __restrict__ Xhi,
        const _Float16* __restrict__ Xlo, int Cpad, int bbase,
        float* __restrict__ G0, float* __restrict__ G1)
{
  __shared__ half8 AsH[2][128][4]; __shared__ half8 AsL[2][128][4];
  __shared__ half8 BsH[2][128][4]; __shared__ half8 BsL[2][128][4];
  int wg = blockIdx.x;                  // 0..511
  int id2 = (wg & 7)*64 + (wg >> 3);    // chunked re-linearize (bijective)
  int bl = id2 >> 8;                    // batch-local 0/1
  int j  = (id2 >> 4) & 15;            // n-tile
  int i  = id2 & 15;                    // m-tile
  int b  = bbase + bl;
  float* G = bl ? G1 : G0;
  const _Float16* Hb = Xhi + (size_t)(b<<11)*Cpad;
  const _Float16* Lb = Xlo + (size_t)(b<<11)*Cpad;
  int m0 = i*128, n0 = j*128;
  int tid = threadIdx.x;
  int w = tid>>6, lane = tid&63;
  int wm = w>>1, wn = w&1;
  int quad = lane>>4, col = lane&15;
  int wbase = w*128;                    // staging slice base (in cid units)
  f32x4 acc[4][4];
  #pragma unroll
  for (int a=0;a<4;++a)
    #pragma unroll
    for (int c2=0;c2<4;++c2) acc[a][c2] = (f32x4){0.f,0.f,0.f,0.f};

  auto stageg = [&](int buf, int k0){
    #pragma unroll
    for (int s=0;s<2;++s){
      int cid = wbase + s*64 + lane;
      int row = cid>>2, kc = cid&3;
      size_t ao = (size_t)(n0+row)*Cpad + k0 + kc*8;
      size_t bo = (size_t)(m0+row)*Cpad + k0 + kc*8;
      int lo = (wbase + s*64)*16;       // wave-uniform LDS byte base
      gl_lds16(Hb + ao, (char*)&AsH[buf][0][0] + lo);
      gl_lds16(Lb + ao, (char*)&AsL[buf][0][0] + lo);
      gl_lds16(Hb + bo, (char*)&BsH[buf][0][0] + lo);
      gl_lds16(Lb + bo, (char*)&BsL[buf][0][0] + lo);
    }
  };

  int NT = Cpad >> 5;
  stageg(0, 0);                         // 8 loads in flight
  if (NT > 1) stageg(1, 32);            // 16 in flight
  for (int kt=0; kt<NT; ++kt){
    int buf = kt & 1;
    // wait only THIS buf's 8 loads; next buf's 8 stay in flight (T4)
    if (kt+1 < NT) asm volatile("s_waitcnt vmcnt(8)" ::: "memory");
    else           asm volatile("s_waitcnt vmcnt(0)" ::: "memory");
    __builtin_amdgcn_s_barrier();       // RAW: all waves' loads landed
    __builtin_amdgcn_sched_barrier(0);
    half8 ah[4], al[4], bh[4], blo[4];
    #pragma unroll
    for (int mt=0;mt<4;++mt){ ah[mt] = AsH[buf][wm*64 + mt*16 + col][quad];
                              al[mt] = AsL[buf][wm*64 + mt*16 + col][quad]; }
    #pragma unroll
    for (int nt=0;nt<4;++nt){ bh[nt] = BsH[buf][wn*64 + nt*16 + col][quad];
                              blo[nt] = BsL[buf][wn*64 + nt*16 + col][quad]; }
    #pragma unroll
    for (int mt=0;mt<4;++mt)
      #pragma unroll
      for (int nt=0;nt<4;++nt){
        acc[mt][nt] = __builtin_amdgcn_mfma_f32_16x16x32_f16(ah[mt], bh[nt], acc[mt][nt], 0, 0, 0);
        acc[mt][nt] = __builtin_amdgcn_mfma_f32_16x16x32_f16(ah[mt], blo[nt], acc[mt][nt], 0, 0, 0);
        acc[mt][nt] = __builtin_amdgcn_mfma_f32_16x16x32_f16(al[mt], bh[nt], acc[mt][nt], 0, 0, 0);
      }
    __builtin_amdgcn_sched_barrier(0);
    __builtin_amdgcn_s_barrier();       // WAR: all waves done reading buf
    if (kt+2 < NT) stageg(buf, (kt+2)<<5);  // overwrite buf for tile kt+2
  }
  // C/D layout: col(m within 16)=lane&15, row(n within 16)=quad*4+r
  #pragma unroll
  for (int mt=0;mt<4;++mt){
    #pragma unroll
    for (int r=0;r<4;++r){
      int n = n0 + wm*64 + mt*16 + quad*4 + r;
      #pragma unroll
      for (int nt=0;nt<4;++nt){
        int m = m0 + wn*64 + nt*16 + col;
        G[(size_t)n*2048 + m] = acc[mt][nt][r];
      }
    }
  }
}

// ---------------- edge-conv projection on MFMA: Y(n,o') = X(n,:)·Wcat(o',:) ----------------
// o' in [0,2O): rows [0,O)=Wd -> V, rows [O,2O)=Wc-Wd -> U.
// Same 128x128 tile + counted-vmcnt pipeline as k_gram.
// R7: 1D grid (64*NY) + XCD-chunked decode: id2 = o_t*64 + b*16 + n_t.
__global__ __launch_bounds__(256) void k_vu_mfma(const _Float16* __restrict__ Xh,
        const _Float16* __restrict__ Xl, const _Float16* __restrict__ Wh,
        const _Float16* __restrict__ Wl, int Cpad, int O,
        float* __restrict__ V, float* __restrict__ U)
{
  __shared__ half8 AsH[2][128][4]; __shared__ half8 AsL[2][128][4];
  __shared__ half8 BsH[2][128][4]; __shared__ half8 BsL[2][128][4];
  int wg = blockIdx.x;
  int NY = gridDim.x >> 6;                   // (2O)/128
  int id2 = (wg & 7)*(NY<<3) + (wg >> 3);    // chunked re-linearize
  int o_t = id2 >> 6;                        // 0..NY-1
  int b   = (id2 >> 4) & 3;
  int n_t = id2 & 15;
  const _Float16* Hb = Xh + (size_t)(b<<11)*Cpad;
  const _Float16* Lb = Xl + (size_t)(b<<11)*Cpad;
  int n0 = n_t*128, o0 = o_t*128;            // o0 in o' space
  int tid = threadIdx.x;
  int w = tid>>6, lane = tid&63;
  int wm = w>>1, wn = w&1;
  int quad = lane>>4, col = lane&15;
  int wbase = w*128;
  f32x4 acc[4][4];
  #pragma unroll
  for (int i=0;i<4;++i)
    #pragma unroll
    for (int j=0;j<4;++j) acc[i][j] = (f32x4){0.f,0.f,0.f,0.f};

  auto stagev = [&](int buf, int k0){
    #pragma unroll
    for (int i=0;i<2;++i){
      int cid = wbase + i*64 + lane;
      int row = cid>>2, kc = cid&3;
      size_t ao = (size_t)(n0+row)*Cpad + k0 + kc*8;
      size_t bo = (size_t)(o0+row)*Cpad + k0 + kc*8;
      int lo = (wbase + i*64)*16;
      gl_lds16(Hb + ao, (char*)&AsH[buf][0][0] + lo);
      gl_lds16(Lb + ao, (char*)&AsL[buf][0][0] + lo);
      gl_lds16(Wh + bo, (char*)&BsH[buf][0][0] + lo);
      gl_lds16(Wl + bo, (char*)&BsL[buf][0][0] + lo);
    }
  };

  int NT = Cpad >> 5;
  stagev(0, 0);
  if (NT > 1) stagev(1, 32);
  for (int kt=0; kt<NT; ++kt){
    int buf = kt & 1;
    if (kt+1 < NT) asm volatile("s_waitcnt vmcnt(8)" ::: "memory");
    else           asm volatile("s_waitcnt vmcnt(0)" ::: "memory");
    __builtin_amdgcn_s_barrier();
    __builtin_amdgcn_sched_barrier(0);
    half8 ah[4], al[4], bh[4], blo[4];
    #pragma unroll
    for (int mt=0;mt<4;++mt){ ah[mt] = AsH[buf][wm*64 + mt*16 + col][quad];
                              al[mt] = AsL[buf][wm*64 + mt*16 + col][quad]; }
    #pragma unroll
    for (int nt=0;nt<4;++nt){ bh[nt] = BsH[buf][wn*64 + nt*16 + col][quad];
                              blo[nt] = BsL[buf][wn*64 + nt*16 + col][quad]; }
    #pragma unroll
    for (int mt=0;mt<4;++mt)
      #pragma unroll
      for (int nt=0;nt<4;++nt){
        acc[mt][nt] = __builtin_amdgcn_mfma_f32_16x16x32_f16(ah[mt], bh[nt], acc[mt][nt], 0, 0, 0);
        acc[mt][nt] = __builtin_amdgcn_mfma_f32_16x16x32_f16(ah[mt], blo[nt], acc[mt][nt], 0, 0, 0);
        acc[mt][nt] = __builtin_amdgcn_mfma_f32_16x16x32_f16(al[mt], bh[nt], acc[mt][nt], 0, 0, 0);
      }
    __builtin_amdgcn_sched_barrier(0);
    __builtin_amdgcn_s_barrier();
    if (kt+2 < NT) stagev(buf, (kt+2)<<5);
  }
  // epilogue: (n, o') -> V if o'<O else U
  #pragma unroll
  for (int mt=0;mt<4;++mt){
    #pragma unroll
    for (int r=0;r<4;++r){
      int n = n0 + wm*64 + mt*16 + quad*4 + r;
      size_t R = (size_t)(b<<11) + n;
      #pragma unroll
      for (int nt=0;nt<4;++nt){
        int op = o0 + wn*64 + nt*16 + col;
        float y = acc[mt][nt][r];
        if (op < O) V[R*O + op] = y;
        else        U[R*O + op - O] = y;
      }
    }
  }
}

// ---------------- top-20 selection from Gram row ----------------
// 32 register slots per lane: slot (ch,cp) <-> candidate m = ch*256 + (lane<<2) + cp
#define KNN_CH(OPC) OPC(0) OPC(1) OPC(2) OPC(3) OPC(4) OPC(5) OPC(6) OPC(7)
#define DECL_CH(ch) float d##ch##_0,d##ch##_1,d##ch##_2,d##ch##_3;
#define LOADG_CH(ch) { float4 g = *(const float4*)(grow + (ch)*256 + base); \
  float4 xm = *(const float4*)(x2b + (ch)*256 + base); \
  d##ch##_0 = x2n + xm.x - 2.f*g.x; d##ch##_1 = x2n + xm.y - 2.f*g.y; \
  d##ch##_2 = x2n + xm.z - 2.f*g.z; d##ch##_3 = x2n + xm.w - 2.f*g.w; }
#define DECL_G(ch) float gv##ch; int gm##ch;
// strict < in ascending slot order -> smallest idx among exact ties
#define MKCH(ch) { gv##ch = d##ch##_0; gm##ch = (ch)*256 + base; \
  if (d##ch##_1 < gv##ch){ gv##ch = d##ch##_1; gm##ch = (ch)*256 + base + 1; } \
  if (d##ch##_2 < gv##ch){ gv##ch = d##ch##_2; gm##ch = (ch)*256 + base + 2; } \
  if (d##ch##_3 < gv##ch){ gv##ch = d##ch##_3; gm##ch = (ch)*256 + base + 3; } }
#define REMCASE(ch) case ch: { \
  if (own){ if (cp==0) d##ch##_0 = FLT_MAX; else if (cp==1) d##ch##_1 = FLT_MAX; \
            else if (cp==2) d##ch##_2 = FLT_MAX; else d##ch##_3 = FLT_MAX; } \
  MKCH(ch) } break;

__global__ __launch_bounds__(256,4) void k_sel(const float* __restrict__ G0,
        const float* __restrict__ G1, const float* __restrict__ X2,
        int bbase, int* __restrict__ IDX)
{
  int tid = threadIdx.x;
  int w = tid >> 6, lane = tid & 63;
  int n = blockIdx.x*4 + w;
  int b = bbase + blockIdx.y;
  const float* grow = (blockIdx.y ? G1 : G0) + (size_t)n*2048;
  const float* x2b  = X2 + (b<<11);
  float x2n = x2b[n];
  int base = lane << 2;
  KNN_CH(DECL_CH)
  KNN_CH(LOADG_CH)
  KNN_CH(DECL_G)
  KNN_CH(MKCH)
  int* op = IDX + ((size_t)(b<<11)+n)*KNN;
  for (int it=0; it<KNN; ++it){
    float v = fminf(fminf(fminf(gv0,gv1),fminf(gv2,gv3)),
                    fminf(fminf(gv4,gv5),fminf(gv6,gv7)));
    #pragma unroll
    for (int s=1; s<64; s<<=1) v = fminf(v, __shfl_xor(v, s));
    int mc = 0x7fffffff;
    mc = (gv7==v) ? gm7 : mc;
    mc = (gv6==v) ? gm6 : mc;
    mc = (gv5==v) ? gm5 : mc;
    mc = (gv4==v) ? gm4 : mc;
    mc = (gv3==v) ? gm3 : mc;
    mc = (gv2==v) ? gm2 : mc;
    mc = (gv1==v) ? gm1 : mc;
    mc = (gv0==v) ? gm0 : mc;
    int m = mc;
    #pragma unroll
    for (int s=1; s<64; s<<=1) m = min(m, __shfl_xor(m, s));
    if (lane==0) op[it] = m;
    int sm = __builtin_amdgcn_readfirstlane(m);
    bool own = (lane == ((sm>>2)&63));
    int cp = sm & 3;
    switch (sm >> 8){ KNN_CH(REMCASE) }
  }
}

// ---------------- single gather pass: ymax/ymin per (b,n,o) + channel sum/sumsq ----------------
// OC-wide o-chunk per block, XCD-affinity via blockIdx%8 round-robin
// (b = xcd>>1, o-half = xcd&1) -> per-XCD random-read working set of V is
// 2048 x OC x 4B (<= 2MB), L2-resident after compulsory misses.
template<int OC, int CHN>
__global__ __launch_bounds__(256) void k_gather(const float* __restrict__ V,
        const float* __restrict__ U, const int* __restrict__ IDX,
        float* __restrict__ YMX, float* __restrict__ YMN,
        float* __restrict__ SUM, float* __restrict__ SUMSQ)
{
  constexpr int O = OC*CHN;
  constexpr int NT = 8;
  constexpr int NSTEP = 256/OC;       // threads sharing one o column
  __shared__ int sidx[NT*KNN];
  __shared__ float rs[256], rq[256];
  int bid = blockIdx.x;
  int xcd  = bid & 7;                 // HW round-robin wg->XCD (learn_hip m09)
  int b    = xcd >> 1;
  int half = xcd & 1;
  int r    = bid >> 3;
  int ngrp, chunk;
  if (CHN == 1){ ngrp = (half<<7) | r; chunk = 0; }        // r in [0,128)
  else         { ngrp = r & 255; chunk = half*(CHN/2) + (r>>8); }
  int n0 = ngrp * NT;
  int tid = threadIdx.x;
  for (int l = tid; l < NT*KNN; l += 256)
    sidx[l] = IDX[((size_t)(b<<11)+n0)*KNN + l];
  __syncthreads();
  int o  = chunk*OC + (tid & (OC-1));
  int ns = tid / OC;
  const float* Vb = V + (size_t)(b<<11)*O + o;
  float s = 0.f, q = 0.f;
  #pragma unroll
  for (int i = 0; i < NT/NSTEP; ++i){
    int nn = ns + i*NSTEP;
    int n = n0 + nn;
    size_t ub = ((size_t)(b<<11)+n)*O + o;
    float sv = 0.f, sv2 = 0.f, mx = -FLT_MAX, mn = FLT_MAX;
    #pragma unroll
    for (int k=0;k<KNN;++k){
      int m = sidx[nn*KNN+k];
      float v = Vb[(size_t)m*O];
      mx = fmaxf(mx,v); mn = fminf(mn,v);
      sv += v; sv2 = fmaf(v,v,sv2);
    }
    float u = __builtin_nontemporal_load(U + ub);
    __builtin_nontemporal_store(mx + u, YMX + ub);
    __builtin_nontemporal_store(mn + u, YMN + ub);
    s += sv + (float)KNN * u;
    q += sv2 + 2.f*u*sv + (float)KNN*u*u;
  }
  rs[tid] = s; rq[tid] = q;
  __syncthreads();
  if (tid < OC){
    #pragma unroll
    for (int t=1; t<NSTEP; ++t){ s += rs[tid + t*OC]; q += rq[tid + t*OC]; }
    atomicAdd(&SUM[o], s);
    atomicAdd(&SUMSQ[o], q);
  }
}

__global__ void k_finalize(const float* __restrict__ SUM, const float* __restrict__ SUMSQ,
        const float* __restrict__ g, const float* __restrict__ bt,
        int O, float invM, float* __restrict__ SC, float* __restrict__ SH){
  int o = blockIdx.x*256 + threadIdx.x;
  if (o>=O) return;
  float m = SUM[o]*invM;
  float var = SUMSQ[o]*invM - m*m;
  float sc = g[o] * rsqrtf(var + 1e-5f);
  SC[o]=sc; SH[o] = bt[o] - m*sc;
}

// ---------------- apply BN + lrelu to recorded extrema; transpose (b,n,o)->(b,o,n) ----------------
__global__ __launch_bounds__(256) void k_apply(const float* __restrict__ YMX, const float* __restrict__ YMN,
        const float* __restrict__ SC, const float* __restrict__ SH,
        int O, float* __restrict__ OUT)
{
  __shared__ float t[64][65];
  int b = blockIdx.z;
  int o0 = blockIdx.y*64, n0 = blockIdx.x*64;
  int tid = threadIdx.x;
  int lo = tid & 63, ln = tid >> 6;
  float sc = SC[o0+lo], sh = SH[o0+lo];
  for (int nn = ln; nn < 64; nn += 4){
    size_t idx = ((size_t)(b<<11)+n0+nn)*O + o0 + lo;
    float v = (sc >= 0.f) ? YMX[idx] : YMN[idx];
    float y = fmaf(sc, v, sh);
    y = (y > 0.f) ? y : 0.2f*y;
    t[lo][nn] = y;
  }
  __syncthreads();
  for (int oo = ln; oo < 64; oo += 4){
    OUT[(size_t)b*HSTRIDE + (size_t)(o0+oo)*NPTS + n0 + lo] = t[oo][lo];
  }
}

// ---------------- transpose H (b,c,n) fp32 -> Hf16 (b,n,KPAD) f16, zero-pad c>=963 ----------------
__global__ __launch_bounds__(256) void k_h2f16(const float* __restrict__ H, _Float16* __restrict__ Hf){
  __shared__ float t[64][65];
  int b = blockIdx.z;
  int n0 = blockIdx.x*64, c0 = blockIdx.y*64;
  int tid = threadIdx.x; int l = tid & 63, m = tid >> 6;
  for (int cc = m; cc < 64; cc += 4){
    int c = c0 + cc;
    t[cc][l] = (c < CH_H) ? H[(size_t)b*HSTRIDE + (size_t)c*NPTS + n0 + l] : 0.f;
  }
  __syncthreads();
  for (int nn = m; nn < 64; nn += 4){
    int c = c0 + l;
    if (c < KPAD)
      Hf[((size_t)(b<<11)+n0+nn)*KPAD + c] = (_Float16)t[l][nn];
  }
}

// ---------------- w5 -> f16 (+ zero l5 reduction buffers) ----------------
__global__ void k_w5f16(const float* __restrict__ w5, _Float16* __restrict__ Wf,
                        unsigned* __restrict__ z){
  int i = blockIdx.x*256 + threadIdx.x;
  if (i < 12288) z[i] = 0u;                 // SUM5,SUMSQ5,MAXB
  else if (i < 20480) z[i] = 0xFFFFFFFFu;   // MINB
  if (i >= 2048*KPAD) return;
  int o = i / KPAD, c = i - o*KPAD;
  Wf[i] = (c < CH_H) ? (_Float16)w5[(size_t)o*CH_H + c] : (_Float16)0.f;
}

// ---------------- layer-5 GEMM on MFMA, fused BN-stat/max epilogue ----------------
// Counted-vmcnt raw-barrier pipeline, depth-2 prefetch.
// R7: 1D grid (1024) + XCD-chunked decode: id2 = o_t*64 + b*16 + n_t, so
// each XCD re-reads only 2 Wf o-panels (508KB) against all n,b (L2-fits).
__global__ __launch_bounds__(256) void k_l5mfma(const _Float16* __restrict__ Wf,
        const _Float16* __restrict__ Hf,
        float* __restrict__ SUM5, float* __restrict__ SUMSQ5,
        unsigned* __restrict__ MAXB, unsigned* __restrict__ MINB)
{
  __shared__ half8 As[2][128][4];   // [buf][o_row][k-chunk of 8]
  __shared__ half8 Bs[2][128][4];   // [buf][n_row][k-chunk of 8]
  int wg = blockIdx.x;                  // 0..1023
  int id2 = (wg & 7)*128 + (wg >> 3);   // chunked re-linearize (bijective)
  int o_t = id2 >> 6;                   // 0..15
  int b   = (id2 >> 4) & 3;
  int n_t = id2 & 15;
  int n0 = n_t*128, o0 = o_t*128;
  int tid = threadIdx.x;
  int w = tid>>6, lane = tid&63;
  int wm = w>>1, wn = w&1;          // wave grid 2x2
  int quad = lane>>4, col = lane&15;
  int wbase = w*128;                // staging slice base (in cid units)
  f32x4 acc[4][4];
  #pragma unroll
  for (int i=0;i<4;++i)
    #pragma unroll
    for (int j=0;j<4;++j) acc[i][j] = (f32x4){0.f,0.f,0.f,0.f};

  auto stage5 = [&](int buf, int k0){
    #pragma unroll
    for (int i=0;i<2;++i){
      int cid = wbase + i*64 + lane;
      int row = cid>>2, kc = cid&3;
      int lo = (wbase + i*64)*16;   // wave-uniform LDS byte base
      gl_lds16(Wf + (size_t)(o0+row)*KPAD + k0 + kc*8, (char*)&As[buf][0][0] + lo);
      gl_lds16(Hf + ((size_t)(b<<11)+n0+row)*KPAD + k0 + kc*8, (char*)&Bs[buf][0][0] + lo);
    }
  };

  const int NT = KPAD/32;           // 31
  stage5(0, 0);                     // 4 loads in flight
  stage5(1, 32);                    // 8 in flight
  for (int kt=0; kt<NT; ++kt){
    int buf = kt & 1;
    // wait only THIS buf's 4 loads; next buf's 4 stay in flight (T4)
    if (kt+1 < NT) asm volatile("s_waitcnt vmcnt(4)" ::: "memory");
    else           asm volatile("s_waitcnt vmcnt(0)" ::: "memory");
    __builtin_amdgcn_s_barrier();   // RAW: all waves' loads landed
    __builtin_amdgcn_sched_barrier(0);
    half8 af[4], bf[4];
    #pragma unroll
    for (int mt=0;mt<4;++mt) af[mt] = As[buf][wm*64 + mt*16 + col][quad];
    #pragma unroll
    for (int nt=0;nt<4;++nt) bf[nt] = Bs[buf][wn*64 + nt*16 + col][quad];
    #pragma unroll
    for (int mt=0;mt<4;++mt)
      #pragma unroll
      for (int nt=0;nt<4;++nt)
        acc[mt][nt] = __builtin_amdgcn_mfma_f32_16x16x32_f16(af[mt], bf[nt], acc[mt][nt], 0, 0, 0);
    __builtin_amdgcn_sched_barrier(0);
    __builtin_amdgcn_s_barrier();   // WAR: all waves done reading buf
    if (kt+2 < NT) stage5(buf, (kt+2)*32);  // overwrite buf for tile kt+2
  }
  // epilogue: C/D layout col(n)=lane&15, row(o)=quad*4+reg
  #pragma unroll
  for (int mt=0;mt<4;++mt){
    #pragma unroll
    for (int r=0;r<4;++r){
      float s=0.f, q=0.f, mx=-FLT_MAX, mn=FLT_MAX;
      #pragma unroll
      for (int nt=0;nt<4;++nt){
        float y = acc[mt][nt][r];
        s += y; q = fmaf(y,y,q);
        mx = fmaxf(mx,y); mn = fminf(mn,y);
      }
      #pragma unroll
      for (int d=8; d; d>>=1){
        s += __shfl_down(s,(unsigned)d,16);
        q += __shfl_down(q,(unsigned)d,16);
        mx = fmaxf(mx,__shfl_down(mx,(unsigned)d,16));
        mn = fminf(mn,__shfl_down(mn,(unsigned)d,16));
      }
      if (col==0){
        int o = o0 + wm*64 + mt*16 + quad*4 + r;
        atomicAdd(&SUM5[o], s);
        atomicAdd(&SUMSQ5[o], q);
        atomicMax(&MAXB[(b<<11)+o], fenc(mx));
        atomicMin(&MINB[(b<<11)+o], fenc(mn));
      }
    }
  }
}

// ---------------- layer-5 finalize: BN + leaky_relu + max over n -> P (B,2048) ----------------
__global__ void k_l5_final(const float* __restrict__ SUM5, const float* __restrict__ SUMSQ5,
        const unsigned* __restrict__ MAXB, const unsigned* __restrict__ MINB,
        const float* __restrict__ g5, const float* __restrict__ b5, float* __restrict__ P)
{
  int o = blockIdx.x*256 + threadIdx.x;
  if (o>=2048) return;
  float m = SUM5[o]*(1.f/8192.f);
  float var = SUMSQ5[o]*(1.f/8192.f) - m*m;
  float sc = g5[o] * rsqrtf(var + 1e-5f);
  float sh = b5[o] - m*sc;
  for (int b=0;b<4;++b){
    float mx = fdec(MAXB[b*2048+o]);
    float mn = fdec(MINB[b*2048+o]);
    float v = (sc >= 0.f) ? fmaf(sc,mx,sh) : fmaf(sc,mn,sh);
    v = (v > 0.f) ? v : 0.2f*v;
    P[b*2048 + o] = v;
  }
}

// ---------------- small FC: Y(B,O) = W(O,Cin)*Z(B,Cin) + bias, one wave per o ----------------
__global__ __launch_bounds__(256) void k_fc(const float* __restrict__ W, const float* __restrict__ bias,
        const float* __restrict__ Z, int Cin, int O, float* __restrict__ Y)
{
  int o = blockIdx.x*4 + (threadIdx.x>>6);
  int lane = threadIdx.x & 63;
  if (o >= O) return;
  const float* wr = W + (size_t)o*Cin;
  float a0=0.f,a1=0.f,a2=0.f,a3=0.f;
  for (int c=lane;c<Cin;c+=64){
    float w = wr[c];
    a0 = fmaf(w, Z[c],        a0);
    a1 = fmaf(w, Z[Cin+c],    a1);
    a2 = fmaf(w, Z[2*Cin+c],  a2);
    a3 = fmaf(w, Z[3*Cin+c],  a3);
  }
  #pragma unroll
  for (int s=32;s;s>>=1){
    a0 += __shfl_down(a0,(unsigned)s); a1 += __shfl_down(a1,(unsigned)s);
    a2 += __shfl_down(a2,(unsigned)s); a3 += __shfl_down(a3,(unsigned)s);
  }
  if (lane==0){
    float bb = bias[o];
    Y[o]=a0+bb; Y[O+o]=a1+bb; Y[2*O+o]=a2+bb; Y[3*O+o]=a3+bb;
  }
}

// ---------------- BN over batch (4 samples) + relu ----------------
__global__ void k_bn4(const float* __restrict__ Y, const float* __restrict__ g, const float* __restrict__ bt,
                      int O, float* __restrict__ Z, int zstride, int zoff)
{
  int o = blockIdx.x*256 + threadIdx.x;
  if (o>=O) return;
  float v0=Y[o], v1=Y[O+o], v2=Y[2*O+o], v3=Y[3*O+o];
  float m = 0.25f*(v0+v1+v2+v3);
  float d0=v0-m, d1=v1-m, d2=v2-m, d3=v3-m;
  float var = 0.25f*(d0*d0+d1*d1+d2*d2+d3*d3);
  float sc = g[o] * rsqrtf(var + 1e-5f);
  float sh = bt[o] - m*sc;
  Z[0*zstride+zoff+o] = fmaxf(fmaf(sc,v0,sh), 0.f);
  Z[1*zstride+zoff+o] = fmaxf(fmaf(sc,v1,sh), 0.f);
  Z[2*zstride+zoff+o] = fmaxf(fmaf(sc,v2,sh), 0.f);
  Z[3*zstride+zoff+o] = fmaxf(fmaf(sc,v3,sh), 0.f);
}

__global__ void k_copy_p(const float* __restrict__ P, float* __restrict__ Z){
  int i = blockIdx.x*256 + threadIdx.x;   // < 4*2048
  int b = i>>11, o = i&2047;
  Z[b*4096 + 2048 + o] = P[i];
}

// ---------------- final: y8 = w8*z7 + wb8, tanh, fp32 out (4,400) ----------------
__global__ __launch_bounds__(256) void k_final(const float* __restrict__ W8, const float* __restrict__ wb8,
        const float* __restrict__ Z7, float* __restrict__ out)
{
  int o = blockIdx.x*4 + (threadIdx.x>>6);
  int lane = threadIdx.x & 63;
  if (o >= 400) return;
  const float* wr = W8 + (size_t)o*4096;
  float a0=0.f,a1=0.f,a2=0.f,a3=0.f;
  for (int c=lane;c<4096;c+=64){
    float w = wr[c];
    a0 = fmaf(w, Z7[c],        a0);
    a1 = fmaf(w, Z7[4096+c],   a1);
    a2 = fmaf(w, Z7[2*4096+c], a2);
    a3 = fmaf(w, Z7[3*4096+c], a3);
  }
  #pragma unroll
  for (int s=32;s;s>>=1){
    a0 += __shfl_down(a0,(unsigned)s); a1 += __shfl_down(a1,(unsigned)s);
    a2 += __shfl_down(a2,(unsigned)s); a3 += __shfl_down(a3,(unsigned)s);
  }
  if (lane==0){
    float bb = wb8[o];
    out[0*400+o] = tanhf(a0+bb);
    out[1*400+o] = tanhf(a1+bb);
    out[2*400+o] = tanhf(a2+bb);
    out[3*400+o] = tanhf(a3+bb);
  }
}

extern "C" void kernel_launch(void* const* d_in, const int* in_sizes, int n_in,
                              void* d_out, int out_size, void* d_ws, size_t ws_size,
                              hipStream_t stream)
{
  const float* x   = (const float*)d_in[0];
  const float* w_e[4]  = {(const float*)d_in[1], (const float*)d_in[4], (const float*)d_in[7], (const float*)d_in[10]};
  const float* g_e[4]  = {(const float*)d_in[2], (const float*)d_in[5], (const float*)d_in[8], (const float*)d_in[11]};
  const float* b_e[4]  = {(const float*)d_in[3], (const float*)d_in[6], (const float*)d_in[9], (const float*)d_in[12]};
  const float* w5  = (const float*)d_in[13];
  const float* g5  = (const float*)d_in[14];
  const float* b5  = (const float*)d_in[15];
  const float* w6  = (const float*)d_in[16];
  const float* wb6 = (const float*)d_in[17];
  const float* g6  = (const float*)d_in[18];
  const float* b6  = (const float*)d_in[19];
  const float* w7  = (const float*)d_in[20];
  const float* wb7 = (const float*)d_in[21];
  const float* g7  = (const float*)d_in[22];
  const float* b7  = (const float*)d_in[23];
  const float* w8  = (const float*)d_in[24];
  const float* wb8 = (const float*)d_in[25];

  float* WS = (float*)d_ws;
  float* H    = WS;                          // 7,888,896
  float* V    = WS + 7888896;                // 4,194,304
  float* U    = V  + 4194304;                // 4,194,304
  float* YMX  = U  + 4194304;                // 4,194,304
  float* YMN  = YMX+ 4194304;                // 4,194,304
  int*   IDX  = (int*)(YMN + 4194304);       //   163,840 ints
  float* X2   = (float*)(IDX + 163840);      //     8,192
  float* SUM  = X2 + 8192;                   //       512
  float* SUMSQ= SUM + 512;                   //       512
  float* SC   = SUMSQ + 512;                 //       512
  float* SH   = SC + 512;                    //       512
  float* SUM5 = SH + 512;                    //     2,048
  float* SUMSQ5 = SUM5 + 2048;               //     2,048
  unsigned* MAXB = (unsigned*)(SUMSQ5 + 2048); //   8,192
  unsigned* MINB = MAXB + 8192;              //     8,192
  float* P    = (float*)(MINB + 8192);       //     8,192
  float* Y6   = P + 8192;                    //     8,192
  float* Z    = Y6 + 8192;                   //    16,384
  float* Y7   = Z + 16384;                   //    16,384
  float* Z7   = Y7 + 16384;                  //    16,384
  // aliases (stage-disjoint lifetimes):
  _Float16* Hf  = (_Float16*)V;              // l5 operand, after edge stages
  _Float16* Wf  = (_Float16*)U;              // l5 operand
  // knn/edge split operands live in YMN (dead until k_gather overwrites);
  // Gram G1 lives in V (dead until k_vu_mfma writes it, after k_sel reads).
  _Float16* Xhi  = (_Float16*)YMN;                 // 4 MB
  _Float16* Xlo  = Xhi + (size_t)4*2048*256;       // 4 MB
  _Float16* Wsph = Xlo + (size_t)4*2048*256;       // 0.5 MB (max 1024x256)
  _Float16* Wspl = Wsph + 1024*256;                // 0.5 MB
  float* G0 = YMX;                           // per-batch Gram (16.8 MB each)
  float* G1 = V;

  k_convert<<<96,256,0,stream>>>(x, H);

  const int Cin_[4]  = {3,64,128,256};
  const int Cpad_[4] = {32,64,128,256};
  const int O_[4]    = {64,128,256,512};
  const int ioff_[4] = {0,3,67,195};
  const int ooff_[4] = {3,67,195,451};

  for (int l=0;l<4;++l){
    const float* Xl = H + (size_t)ioff_[l]*NPTS;
    int C = Cin_[l], Cpad = Cpad_[l], O = O_[l];
    k_norms<<<32,256,0,stream>>>(Xl, C, X2, SUM);
    dim3 gxs(32, (Cpad+63)/64, 4);
    k_xsplit<<<gxs,256,0,stream>>>(Xl, C, Cpad, Xhi, Xlo);
    k_wsplit<<<(2*O*Cpad+255)/256,256,0,stream>>>(w_e[l], C, Cpad, O, Wsph, Wspl);
    k_gram<<<512,256,0,stream>>>(Xhi, Xlo, Cpad, 0, G0, G1);
    dim3 gsl(512,2);
    k_sel<<<gsl,256,0,stream>>>(G0, G1, X2, 0, IDX);
    k_gram<<<512,256,0,stream>>>(Xhi, Xlo, Cpad, 2, G0, G1);
    k_sel<<<gsl,256,0,stream>>>(G0, G1, X2, 2, IDX);
    k_vu_mfma<<<64*(2*O/128),256,0,stream>>>(Xhi, Xlo, Wsph, Wspl, Cpad, O, V, U);
    if (O == 64)
      k_gather<64,1><<<1024,256,0,stream>>>(V, U, IDX, YMX, YMN, SUM, SUMSQ);
    else if (O == 128)
      k_gather<128,1><<<1024,256,0,stream>>>(V, U, IDX, YMX, YMN, SUM, SUMSQ);
    else if (O == 256)
      k_gather<128,2><<<2048,256,0,stream>>>(V, U, IDX, YMX, YMN, SUM, SUMSQ);
    else
      k_gather<128,4><<<4096,256,0,stream>>>(V, U, IDX, YMX, YMN, SUM, SUMSQ);
    k_finalize<<<2,256,0,stream>>>(SUM, SUMSQ, g_e[l], b_e[l], O, 1.f/163840.f, SC, SH);
    dim3 gap(32, O/64, 4);
    k_apply<<<gap,256,0,stream>>>(YMX, YMN, SC, SH, O, H + (size_t)ooff_[l]*NPTS);
  }

  // ---- layer 5 on MFMA ----
  dim3 gtr(32,16,4);
  k_h2f16<<<gtr,256,0,stream>>>(H, Hf);
  k_w5f16<<<(2048*KPAD+255)/256,256,0,stream>>>(w5, Wf, (unsigned*)SUM5);
  k_l5mfma<<<1024,256,0,stream>>>(Wf, Hf, SUM5, SUMSQ5, MAXB, MINB);
  k_l5_final<<<8,256,0,stream>>>(SUM5, SUMSQ5, MAXB, MINB, g5, b5, P);

  k_fc<<<512,256,0,stream>>>(w6, wb6, P, 2048, 2048, Y6);
  k_bn4<<<8,256,0,stream>>>(Y6, g6, b6, 2048, Z, 4096, 0);
  k_copy_p<<<32,256,0,stream>>>(P, Z);
  k_fc<<<1024,256,0,stream>>>(w7, wb7, Z, 4096, 4096, Y7);
  k_bn4<<<16,256,0,stream>>>(Y7, g7, b7, 4096, Z7, 4096, 0);
  k_final<<<100,256,0,stream>>>(w8, wb8, Z7, (float*)d_out);
}

// Round 9
// 1001.268 us; speedup vs baseline: 1.1007x; 1.0247x over previous
//
#include <hip/hip_runtime.h>
#include <float.h>
#include <math.h>

// DGCNN control-points pipeline, fp32 compute; MFMA (f16 hi/lo split) for the
// knn Gram matrix, edge-conv projection, and f16-MFMA for the layer-5 GEMM.
//
// Edge conv decomposition: y[b,o,n,k] = W·[nbr-ctr; ctr]
//   = v[b, idx(n,k), o] + u[b,n,o]   with v = Wd·x, u = (Wc-Wd)·x
// BN is batch-stats. knn: G = X^T X via mfma f16 hi/lo split;
// d = x2[n]+x2[m]-2G; per-wave register top-20 (exact lax.top_k order).
// Layer-5 (2048x963x8192) on matrix cores, BN-stat/max fused via atomics.
//
// R1: k_gather o-chunked + XCD-affinity, nontemporal streams (103us -> gone).
// R2: global_load_lds single-buffered -> regressed (exposed latency). 
// R3: 2-phase dbuf w/ __syncthreads: l5 95->80us.
// R4: counted-vmcnt raw-barrier pipeline. l5 ~77us. 1075->1065.
// R5: k_vu -> MFMA (k_vu_mfma). 1065->1001us.  <-- anchor
// R6: triangular gram REGRESSED (latency-bound blocks; mirror scatter).
// R7: XCD o-chunking REGRESSED: FETCH 39->100MB (concentrated the SMALL
//     operand per XCD; default n%8 map is already at the ~46MB fetch floor).
// R8: revert R6/R7 entirely (R5 grids); l5 only: TRIPLE-buffer LDS, ONE
//     barrier/iter. stage(t+2) targets buf_{(t-1)%3}; the collective top
//     barrier proves all waves consumed buf_{t-1} (ds_reads drain via MFMA
//     lgkm deps before barrier), so the WAR barrier is redundant. 31 fewer
//     barrier drains; LDS 48KB -> 3 blk/CU.

#define NPTS 2048
#define BATCH 4
#define KNN 20
#define CH_H 963
#define KPAD 992              // 963 padded to 31*32
#define HSTRIDE (CH_H*NPTS)   // per-batch element stride of concat buffer H

typedef _Float16 half8 __attribute__((ext_vector_type(8)));
typedef float f32x4 __attribute__((ext_vector_type(4)));

// direct global->LDS 16B DMA; lds dest is wave-uniform base + lane*16
typedef const __attribute__((address_space(1))) unsigned int* gas_p;
typedef __attribute__((address_space(3))) unsigned int* las_p;
__device__ __forceinline__ void gl_lds16(const void* g, void* l){
  __builtin_amdgcn_global_load_lds((gas_p)g, (las_p)l, 16, 0, 0);
}

// order-preserving float<->uint for atomicMax/Min
__device__ __forceinline__ unsigned fenc(float x){
  unsigned u = __float_as_uint(x);
  return (u & 0x80000000u) ? ~u : (u | 0x80000000u);
}
__device__ __forceinline__ float fdec(unsigned u){
  u = (u & 0x80000000u) ? (u ^ 0x80000000u) : ~u;
  return __uint_as_float(u);
}

// ---------------- copy input x (B,3,N) -> H rows [0,3) ----------------
__global__ void k_convert(const float* __restrict__ x, float* __restrict__ H){
  int i = blockIdx.x*256 + threadIdx.x;
  if (i >= BATCH*3*NPTS) return;
  int b = i / (3*NPTS); int r = i % (3*NPTS);
  H[(size_t)b*HSTRIDE + r] = x[i];
}

// ---------------- per-point squared norms (+ zero SUM/SUMSQ for this layer) ----------------
__global__ void k_norms(const float* __restrict__ X, int C, float* __restrict__ X2,
                        float* __restrict__ SUMZ){
  int i = blockIdx.x*256 + threadIdx.x;     // b*2048+n
  if (i < 1024) SUMZ[i] = 0.f;              // SUM[512] ++ SUMSQ[512] contiguous
  int b = i >> 11, n = i & 2047;
  const float* Xb = X + (size_t)b*HSTRIDE + n;
  float s = 0.f;
  for (int c=0;c<C;++c){ float v = Xb[(size_t)c*NPTS]; s = fmaf(v,v,s); }
  X2[i] = s;
}

// ---------------- X (b,c,n) fp32 -> Xhi/Xlo (b,n,Cpad) f16 split ----------------
__global__ __launch_bounds__(256) void k_xsplit(const float* __restrict__ X, int C, int Cpad,
        _Float16* __restrict__ Xhi, _Float16* __restrict__ Xlo)
{
  __shared__ float t[64][65];
  int b = blockIdx.z;
  int n0 = blockIdx.x*64, c0 = blockIdx.y*64;
  int tid = threadIdx.x; int l = tid & 63, m = tid >> 6;
  for (int cc = m; cc < 64; cc += 4){
    int c = c0 + cc;
    t[cc][l] = (c < C) ? X[(size_t)b*HSTRIDE + (size_t)c*NPTS + n0 + l] : 0.f;
  }
  __syncthreads();
  for (int nn = m; nn < 64; nn += 4){
    int c = c0 + l;
    if (c < Cpad){
      float v = t[l][nn];
      _Float16 h = (_Float16)v;
      size_t o = ((size_t)(b<<11)+n0+nn)*Cpad + c;
      Xhi[o] = h;
      Xlo[o] = (_Float16)(v - (float)h);
    }
  }
}

// ---------------- W (O,2C) fp32 -> Wcat=[Wd; Wc-Wd] (2O,Cpad) f16 hi/lo ----------------
__global__ void k_wsplit(const float* __restrict__ W, int C, int Cpad, int O,
        _Float16* __restrict__ Wh, _Float16* __restrict__ Wl){
  int i = blockIdx.x*256 + threadIdx.x;
  if (i >= 2*O*Cpad) return;
  int op = i / Cpad, c = i - op*Cpad;
  float v = 0.f;
  if (c < C){
    const float* wr = W + (size_t)(op < O ? op : op - O)*(2*C);
    v = (op < O) ? wr[c] : (wr[C+c] - wr[c]);
  }
  _Float16 h = (_Float16)v;
  Wh[i] = h; Wl[i] = (_Float16)(v - (float)h);
}

// ---------------- Gram via MFMA: G[n][m] = sum_c X[n][c]*X[m][c] ----------------
// 128x128 tile, 4 waves x (64x64); 3 MFMAs (hh,hl,lh) per fragment pair.
// Counted-vmcnt raw-barrier pipeline, depth-2 prefetch (R4 form, proven).
__global__ __launch_bounds__(256) void k_gram(const _Float16* __restrict__ Xhi,
        const _Float16* __restrict__ Xlo, int Cpad, int bbase,
        float* __restrict__ G0, float* __restrict__ G1)
{
  __shared__ half8 AsH[2][128][4]; __shared__ half8 AsL[2][128][4];
  __shared__ half8 BsH[2][128][4]; __shared__ half8 BsL[2][128][4];
  int bl = blockIdx.z;
  int b  = bbase + bl;
  float* G = bl ? G1 : G0;
  const _Float16* Hb = Xhi + (size_t)(b<<11)*Cpad;
  const _Float16* Lb = Xlo + (size_t)(b<<11)*Cpad;
  int m0 = blockIdx.x*128, n0 = blockIdx.y*128;
  int tid = threadIdx.x;
  int w = tid>>6, lane = tid&63;
  int wm = w>>1, wn = w&1;
  int quad = lane>>4, col = lane&15;
  int wbase = w*128;                    // staging slice base (in cid units)
  f32x4 acc[4][4];
  #pragma unroll
  for (int a=0;a<4;++a)
    #pragma unroll
    for (int c2=0;c2<4;++c2) acc[a][c2] = (f32x4){0.f,0.f,0.f,0.f};

  auto stageg = [&](int buf, int k0){
    #pragma unroll
    for (int s=0;s<2;++s){
      int cid = wbase + s*64 + lane;
      int row = cid>>2, kc = cid&3;
      size_t ao = (size_t)(n0+row)*Cpad + k0 + kc*8;
      size_t bo = (size_t)(m0+row)*Cpad + k0 + kc*8;
      int lo = (wbase + s*64)*16;       // wave-uniform LDS byte base
      gl_lds16(Hb + ao, (char*)&AsH[buf][0][0] + lo);
      gl_lds16(Lb + ao, (char*)&AsL[buf][0][0] + lo);
      gl_lds16(Hb + bo, (char*)&BsH[buf][0][0] + lo);
      gl_lds16(Lb + bo, (char*)&BsL[buf][0][0] + lo);
    }
  };

  int NT = Cpad >> 5;
  stageg(0, 0);                         // 8 loads in flight
  if (NT > 1) stageg(1, 32);            // 16 in flight
  for (int kt=0; kt<NT; ++kt){
    int buf = kt & 1;
    // wait only THIS buf's 8 loads; next buf's 8 stay in flight (T4)
    if (kt+1 < NT) asm volatile("s_waitcnt vmcnt(8)" ::: "memory");
    else           asm volatile("s_waitcnt vmcnt(0)" ::: "memory");
    __builtin_amdgcn_s_barrier();       // RAW: all waves' loads landed
    __builtin_amdgcn_sched_barrier(0);
    half8 ah[4], al[4], bh[4], blo[4];
    #pragma unroll
    for (int mt=0;mt<4;++mt){ ah[mt] = AsH[buf][wm*64 + mt*16 + col][quad];
                              al[mt] = AsL[buf][wm*64 + mt*16 + col][quad]; }
    #pragma unroll
    for (int nt=0;nt<4;++nt){ bh[nt] = BsH[buf][wn*64 + nt*16 + col][quad];
                              blo[nt] = BsL[buf][wn*64 + nt*16 + col][quad]; }
    #pragma unroll
    for (int mt=0;mt<4;++mt)
      #pragma unroll
      for (int nt=0;nt<4;++nt){
        acc[mt][nt] = __builtin_amdgcn_mfma_f32_16x16x32_f16(ah[mt], bh[nt], acc[mt][nt], 0, 0, 0);
        acc[mt][nt] = __builtin_amdgcn_mfma_f32_16x16x32_f16(ah[mt], blo[nt], acc[mt][nt], 0, 0, 0);
        acc[mt][nt] = __builtin_amdgcn_mfma_f32_16x16x32_f16(al[mt], bh[nt], acc[mt][nt], 0, 0, 0);
      }
    __builtin_amdgcn_sched_barrier(0);
    __builtin_amdgcn_s_barrier();       // WAR: all waves done reading buf
    if (kt+2 < NT) stageg(buf, (kt+2)<<5);  // overwrite buf for tile kt+2
  }
  // C/D layout: col(m within 16)=lane&15, row(n within 16)=quad*4+r
  #pragma unroll
  for (int mt=0;mt<4;++mt){
    #pragma unroll
    for (int r=0;r<4;++r){
      int n = n0 + wm*64 + mt*16 + quad*4 + r;
      #pragma unroll
      for (int nt=0;nt<4;++nt){
        int m = m0 + wn*64 + nt*16 + col;
        G[(size_t)n*2048 + m] = acc[mt][nt][r];
      }
    }
  }
}

// ---------------- edge-conv projection on MFMA: Y(n,o') = X(n,:)·Wcat(o',:) ----------------
// o' in [0,2O): rows [0,O)=Wd -> V, rows [O,2O)=Wc-Wd -> U.  (R5 form)
__global__ __launch_bounds__(256) void k_vu_mfma(const _Float16* __restrict__ Xh,
        const _Float16* __restrict__ Xl, const _Float16* __restrict__ Wh,
        const _Float16* __restrict__ Wl, int Cpad, int O,
        float* __restrict__ V, float* __restrict__ U)
{
  __shared__ half8 AsH[2][128][4]; __shared__ half8 AsL[2][128][4];
  __shared__ half8 BsH[2][128][4]; __shared__ half8 BsL[2][128][4];
  int b = blockIdx.z;
  const _Float16* Hb = Xh + (size_t)(b<<11)*Cpad;
  const _Float16* Lb = Xl + (size_t)(b<<11)*Cpad;
  int n0 = blockIdx.x*128, o0 = blockIdx.y*128;   // o0 in o' space
  int tid = threadIdx.x;
  int w = tid>>6, lane = tid&63;
  int wm = w>>1, wn = w&1;
  int quad = lane>>4, col = lane&15;
  int wbase = w*128;
  f32x4 acc[4][4];
  #pragma unroll
  for (int i=0;i<4;++i)
    #pragma unroll
    for (int j=0;j<4;++j) acc[i][j] = (f32x4){0.f,0.f,0.f,0.f};

  auto stagev = [&](int buf, int k0){
    #pragma unroll
    for (int i=0;i<2;++i){
      int cid = wbase + i*64 + lane;
      int row = cid>>2, kc = cid&3;
      size_t ao = (size_t)(n0+row)*Cpad + k0 + kc*8;
      size_t bo = (size_t)(o0+row)*Cpad + k0 + kc*8;
      int lo = (wbase + i*64)*16;
      gl_lds16(Hb + ao, (char*)&AsH[buf][0][0] + lo);
      gl_lds16(Lb + ao, (char*)&AsL[buf][0][0] + lo);
      gl_lds16(Wh + bo, (char*)&BsH[buf][0][0] + lo);
      gl_lds16(Wl + bo, (char*)&BsL[buf][0][0] + lo);
    }
  };

  int NT = Cpad >> 5;
  stagev(0, 0);
  if (NT > 1) stagev(1, 32);
  for (int kt=0; kt<NT; ++kt){
    int buf = kt & 1;
    if (kt+1 < NT) asm volatile("s_waitcnt vmcnt(8)" ::: "memory");
    else           asm volatile("s_waitcnt vmcnt(0)" ::: "memory");
    __builtin_amdgcn_s_barrier();
    __builtin_amdgcn_sched_barrier(0);
    half8 ah[4], al[4], bh[4], blo[4];
    #pragma unroll
    for (int mt=0;mt<4;++mt){ ah[mt] = AsH[buf][wm*64 + mt*16 + col][quad];
                              al[mt] = AsL[buf][wm*64 + mt*16 + col][quad]; }
    #pragma unroll
    for (int nt=0;nt<4;++nt){ bh[nt] = BsH[buf][wn*64 + nt*16 + col][quad];
                              blo[nt] = BsL[buf][wn*64 + nt*16 + col][quad]; }
    #pragma unroll
    for (int mt=0;mt<4;++mt)
      #pragma unroll
      for (int nt=0;nt<4;++nt){
        acc[mt][nt] = __builtin_amdgcn_mfma_f32_16x16x32_f16(ah[mt], bh[nt], acc[mt][nt], 0, 0, 0);
        acc[mt][nt] = __builtin_amdgcn_mfma_f32_16x16x32_f16(ah[mt], blo[nt], acc[mt][nt], 0, 0, 0);
        acc[mt][nt] = __builtin_amdgcn_mfma_f32_16x16x32_f16(al[mt], bh[nt], acc[mt][nt], 0, 0, 0);
      }
    __builtin_amdgcn_sched_barrier(0);
    __builtin_amdgcn_s_barrier();
    if (kt+2 < NT) stagev(buf, (kt+2)<<5);
  }
  // epilogue: (n, o') -> V if o'<O else U
  #pragma unroll
  for (int mt=0;mt<4;++mt){
    #pragma unroll
    for (int r=0;r<4;++r){
      int n = n0 + wm*64 + mt*16 + quad*4 + r;
      size_t R = (size_t)(b<<11) + n;
      #pragma unroll
      for (int nt=0;nt<4;++nt){
        int op = o0 + wn*64 + nt*16 + col;
        float y = acc[mt][nt][r];
        if (op < O) V[R*O + op] = y;
        else        U[R*O + op - O] = y;
      }
    }
  }
}

// ---------------- top-20 selection from Gram row ----------------
#define KNN_CH(OPC) OPC(0) OPC(1) OPC(2) OPC(3) OPC(4) OPC(5) OPC(6) OPC(7)
#define DECL_CH(ch) float d##ch##_0,d##ch##_1,d##ch##_2,d##ch##_3;
#define LOADG_CH(ch) { float4 g = *(const float4*)(grow + (ch)*256 + base); \
  float4 xm = *(const float4*)(x2b + (ch)*256 + base); \
  d##ch##_0 = x2n + xm.x - 2.f*g.x; d##ch##_1 = x2n + xm.y - 2.f*g.y; \
  d##ch##_2 = x2n + xm.z - 2.f*g.z; d##ch##_3 = x2n + xm.w - 2.f*g.w; }
#define DECL_G(ch) float gv##ch; int gm##ch;
// strict < in ascending slot order -> smallest idx among exact ties
#define MKCH(ch) { gv##ch = d##ch##_0; gm##ch = (ch)*256 + base; \
  if (d##ch##_1 < gv##ch){ gv##ch = d##ch##_1; gm##ch = (ch)*256 + base + 1; } \
  if (d##ch##_2 < gv##ch){ gv##ch = d##ch##_2; gm##ch = (ch)*256 + base + 2; } \
  if (d##ch##_3 < gv##ch){ gv##ch = d##ch##_3; gm##ch = (ch)*256 + base + 3; } }
#define REMCASE(ch) case ch: { \
  if (own){ if (cp==0) d##ch##_0 = FLT_MAX; else if (cp==1) d##ch##_1 = FLT_MAX; \
            else if (cp==2) d##ch##_2 = FLT_MAX; else d##ch##_3 = FLT_MAX; } \
  MKCH(ch) } break;

__global__ __launch_bounds__(256,4) void k_sel(const float* __restrict__ G0,
        const float* __restrict__ G1, const float* __restrict__ X2,
        int bbase, int* __restrict__ IDX)
{
  int tid = threadIdx.x;
  int w = tid >> 6, lane = tid & 63;
  int n = blockIdx.x*4 + w;
  int b = bbase + blockIdx.y;
  const float* grow = (blockIdx.y ? G1 : G0) + (size_t)n*2048;
  const float* x2b  = X2 + (b<<11);
  float x2n = x2b[n];
  int base = lane << 2;
  KNN_CH(DECL_CH)
  KNN_CH(LOADG_CH)
  KNN_CH(DECL_G)
  KNN_CH(MKCH)
  int* op = IDX + ((size_t)(b<<11)+n)*KNN;
  for (int it=0; it<KNN; ++it){
    float v = fminf(fminf(fminf(gv0,gv1),fminf(gv2,gv3)),
                    fminf(fminf(gv4,gv5),fminf(gv6,gv7)));
    #pragma unroll
    for (int s=1; s<64; s<<=1) v = fminf(v, __shfl_xor(v, s));
    int mc = 0x7fffffff;
    mc = (gv7==v) ? gm7 : mc;
    mc = (gv6==v) ? gm6 : mc;
    mc = (gv5==v) ? gm5 : mc;
    mc = (gv4==v) ? gm4 : mc;
    mc = (gv3==v) ? gm3 : mc;
    mc = (gv2==v) ? gm2 : mc;
    mc = (gv1==v) ? gm1 : mc;
    mc = (gv0==v) ? gm0 : mc;
    int m = mc;
    #pragma unroll
    for (int s=1; s<64; s<<=1) m = min(m, __shfl_xor(m, s));
    if (lane==0) op[it] = m;
    int sm = __builtin_amdgcn_readfirstlane(m);
    bool own = (lane == ((sm>>2)&63));
    int cp = sm & 3;
    switch (sm >> 8){ KNN_CH(REMCASE) }
  }
}

// ---------------- single gather pass: ymax/ymin per (b,n,o) + channel sum/sumsq ----------------
template<int OC, int CHN>
__global__ __launch_bounds__(256) void k_gather(const float* __restrict__ V,
        const float* __restrict__ U, const int* __restrict__ IDX,
        float* __restrict__ YMX, float* __restrict__ YMN,
        float* __restrict__ SUM, float* __restrict__ SUMSQ)
{
  constexpr int O = OC*CHN;
  constexpr int NT = 8;
  constexpr int NSTEP = 256/OC;       // threads sharing one o column
  __shared__ int sidx[NT*KNN];
  __shared__ float rs[256], rq[256];
  int bid = blockIdx.x;
  int xcd  = bid & 7;                 // HW round-robin wg->XCD (learn_hip m09)
  int b    = xcd >> 1;
  int half = xcd & 1;
  int r    = bid >> 3;
  int ngrp, chunk;
  if (CHN == 1){ ngrp = (half<<7) | r; chunk = 0; }        // r in [0,128)
  else         { ngrp = r & 255; chunk = half*(CHN/2) + (r>>8); }
  int n0 = ngrp * NT;
  int tid = threadIdx.x;
  for (int l = tid; l < NT*KNN; l += 256)
    sidx[l] = IDX[((size_t)(b<<11)+n0)*KNN + l];
  __syncthreads();
  int o  = chunk*OC + (tid & (OC-1));
  int ns = tid / OC;
  const float* Vb = V + (size_t)(b<<11)*O + o;
  float s = 0.f, q = 0.f;
  #pragma unroll
  for (int i = 0; i < NT/NSTEP; ++i){
    int nn = ns + i*NSTEP;
    int n = n0 + nn;
    size_t ub = ((size_t)(b<<11)+n)*O + o;
    float sv = 0.f, sv2 = 0.f, mx = -FLT_MAX, mn = FLT_MAX;
    #pragma unroll
    for (int k=0;k<KNN;++k){
      int m = sidx[nn*KNN+k];
      float v = Vb[(size_t)m*O];
      mx = fmaxf(mx,v); mn = fminf(mn,v);
      sv += v; sv2 = fmaf(v,v,sv2);
    }
    float u = __builtin_nontemporal_load(U + ub);
    __builtin_nontemporal_store(mx + u, YMX + ub);
    __builtin_nontemporal_store(mn + u, YMN + ub);
    s += sv + (float)KNN * u;
    q += sv2 + 2.f*u*sv + (float)KNN*u*u;
  }
  rs[tid] = s; rq[tid] = q;
  __syncthreads();
  if (tid < OC){
    #pragma unroll
    for (int t=1; t<NSTEP; ++t){ s += rs[tid + t*OC]; q += rq[tid + t*OC]; }
    atomicAdd(&SUM[o], s);
    atomicAdd(&SUMSQ[o], q);
  }
}

__global__ void k_finalize(const float* __restrict__ SUM, const float* __restrict__ SUMSQ,
        const float* __restrict__ g, const float* __restrict__ bt,
        int O, float invM, float* __restrict__ SC, float* __restrict__ SH){
  int o = blockIdx.x*256 + threadIdx.x;
  if (o>=O) return;
  float m = SUM[o]*invM;
  float var = SUMSQ[o]*invM - m*m;
  float sc = g[o] * rsqrtf(var + 1e-5f);
  SC[o]=sc; SH[o] = bt[o] - m*sc;
}

// ---------------- apply BN + lrelu to recorded extrema; transpose (b,n,o)->(b,o,n) ----------------
__global__ __launch_bounds__(256) void k_apply(const float* __restrict__ YMX, const float* __restrict__ YMN,
        const float* __restrict__ SC, const float* __restrict__ SH,
        int O, float* __restrict__ OUT)
{
  __shared__ float t[64][65];
  int b = blockIdx.z;
  int o0 = blockIdx.y*64, n0 = blockIdx.x*64;
  int tid = threadIdx.x;
  int lo = tid & 63, ln = tid >> 6;
  float sc = SC[o0+lo], sh = SH[o0+lo];
  for (int nn = ln; nn < 64; nn += 4){
    size_t idx = ((size_t)(b<<11)+n0+nn)*O + o0 + lo;
    float v = (sc >= 0.f) ? YMX[idx] : YMN[idx];
    float y = fmaf(sc, v, sh);
    y = (y > 0.f) ? y : 0.2f*y;
    t[lo][nn] = y;
  }
  __syncthreads();
  for (int oo = ln; oo < 64; oo += 4){
    OUT[(size_t)b*HSTRIDE + (size_t)(o0+oo)*NPTS + n0 + lo] = t[oo][lo];
  }
}

// ---------------- transpose H (b,c,n) fp32 -> Hf16 (b,n,KPAD) f16, zero-pad c>=963 ----------------
__global__ __launch_bounds__(256) void k_h2f16(const float* __restrict__ H, _Float16* __restrict__ Hf){
  __shared__ float t[64][65];
  int b = blockIdx.z;
  int n0 = blockIdx.x*64, c0 = blockIdx.y*64;
  int tid = threadIdx.x; int l = tid & 63, m = tid >> 6;
  for (int cc = m; cc < 64; cc += 4){
    int c = c0 + cc;
    t[cc][l] = (c < CH_H) ? H[(size_t)b*HSTRIDE + (size_t)c*NPTS + n0 + l] : 0.f;
  }
  __syncthreads();
  for (int nn = m; nn < 64; nn += 4){
    int c = c0 + l;
    if (c < KPAD)
      Hf[((size_t)(b<<11)+n0+nn)*KPAD + c] = (_Float16)t[l][nn];
  }
}

// ---------------- w5 -> f16 (+ zero l5 reduction buffers) ----------------
__global__ void k_w5f16(const float* __restrict__ w5, _Float16* __restrict__ Wf,
                        unsigned* __restrict__ z){
  int i = blockIdx.x*256 + threadIdx.x;
  if (i < 12288) z[i] = 0u;                 // SUM5,SUMSQ5,MAXB
  else if (i < 20480) z[i] = 0xFFFFFFFFu;   // MINB
  if (i >= 2048*KPAD) return;
  int o = i / KPAD, c = i - o*KPAD;
  Wf[i] = (c < CH_H) ? (_Float16)w5[(size_t)o*CH_H + c] : (_Float16)0.f;
}

// ---------------- layer-5 GEMM on MFMA, fused BN-stat/max epilogue ----------------
// R8: TRIPLE-buffered LDS, depth-2 prefetch, ONE barrier per K-iter.
// stage(t+2) -> buf_{(t+2)%3} = buf_{(t-1)%3}; the collective barrier at
// iter t proves all waves consumed buf_{t-1} (their ds_reads drained via
// MFMA lgkm deps before reaching the barrier), so no WAR barrier needed.
__global__ __launch_bounds__(256) void k_l5mfma(const _Float16* __restrict__ Wf,
        const _Float16* __restrict__ Hf,
        float* __restrict__ SUM5, float* __restrict__ SUMSQ5,
        unsigned* __restrict__ MAXB, unsigned* __restrict__ MINB)
{
  __shared__ half8 As[3][128][4];   // [buf][o_row][k-chunk of 8]  (48 KB total)
  __shared__ half8 Bs[3][128][4];   // [buf][n_row][k-chunk of 8]
  int b  = blockIdx.z;
  int n0 = blockIdx.x*128, o0 = blockIdx.y*128;
  int tid = threadIdx.x;
  int w = tid>>6, lane = tid&63;
  int wm = w>>1, wn = w&1;          // wave grid 2x2
  int quad = lane>>4, col = lane&15;
  int wbase = w*128;                // staging slice base (in cid units)
  f32x4 acc[4][4];
  #pragma unroll
  for (int i=0;i<4;++i)
    #pragma unroll
    for (int j=0;j<4;++j) acc[i][j] = (f32x4){0.f,0.f,0.f,0.f};

  auto stage5 = [&](int buf, int k0){
    #pragma unroll
    for (int i=0;i<2;++i){
      int cid = wbase + i*64 + lane;
      int row = cid>>2, kc = cid&3;
      int lo = (wbase + i*64)*16;   // wave-uniform LDS byte base
      gl_lds16(Wf + (size_t)(o0+row)*KPAD + k0 + kc*8, (char*)&As[buf][0][0] + lo);
      gl_lds16(Hf + ((size_t)(b<<11)+n0+row)*KPAD + k0 + kc*8, (char*)&Bs[buf][0][0] + lo);
    }
  };

  const int NT = KPAD/32;           // 31
  stage5(0, 0);                     // 4 loads in flight
  stage5(1, 32);                    // 8 in flight
  int bcur = 0;                     // rotating buffer index (avoid % in loop)
  for (int kt=0; kt<NT; ++kt){
    int buf = bcur;
    // wait only THIS buf's 4 loads; next buf's 4 stay in flight (T4)
    if (kt+1 < NT) asm volatile("s_waitcnt vmcnt(4)" ::: "memory");
    else           asm volatile("s_waitcnt vmcnt(0)" ::: "memory");
    __builtin_amdgcn_s_barrier();   // buf_kt ready; buf_{kt-1} fully consumed
    __builtin_amdgcn_sched_barrier(0);
    if (kt+2 < NT){
      int nb = buf + 2; if (nb >= 3) nb -= 3;   // == (kt+2)%3 == (kt-1)%3
      stage5(nb, (kt+2)*32);
    }
    half8 af[4], bf[4];
    #pragma unroll
    for (int mt=0;mt<4;++mt) af[mt] = As[buf][wm*64 + mt*16 + col][quad];
    #pragma unroll
    for (int nt=0;nt<4;++nt) bf[nt] = Bs[buf][wn*64 + nt*16 + col][quad];
    #pragma unroll
    for (int mt=0;mt<4;++mt)
      #pragma unroll
      for (int nt=0;nt<4;++nt)
        acc[mt][nt] = __builtin_amdgcn_mfma_f32_16x16x32_f16(af[mt], bf[nt], acc[mt][nt], 0, 0, 0);
    __builtin_amdgcn_sched_barrier(0);
    bcur = bcur + 1; if (bcur == 3) bcur = 0;
  }
  // epilogue: C/D layout col(n)=lane&15, row(o)=quad*4+reg
  #pragma unroll
  for (int mt=0;mt<4;++mt){
    #pragma unroll
    for (int r=0;r<4;++r){
      float s=0.f, q=0.f, mx=-FLT_MAX, mn=FLT_MAX;
      #pragma unroll
      for (int nt=0;nt<4;++nt){
        float y = acc[mt][nt][r];
        s += y; q = fmaf(y,y,q);
        mx = fmaxf(mx,y); mn = fminf(mn,y);
      }
      #pragma unroll
      for (int d=8; d; d>>=1){
        s += __shfl_down(s,(unsigned)d,16);
        q += __shfl_down(q,(unsigned)d,16);
        mx = fmaxf(mx,__shfl_down(mx,(unsigned)d,16));
        mn = fminf(mn,__shfl_down(mn,(unsigned)d,16));
      }
      if (col==0){
        int o = o0 + wm*64 + mt*16 + quad*4 + r;
        atomicAdd(&SUM5[o], s);
        atomicAdd(&SUMSQ5[o], q);
        atomicMax(&MAXB[(b<<11)+o], fenc(mx));
        atomicMin(&MINB[(b<<11)+o], fenc(mn));
      }
    }
  }
}

// ---------------- layer-5 finalize: BN + leaky_relu + max over n -> P (B,2048) ----------------
__global__ void k_l5_final(const float* __restrict__ SUM5, const float* __restrict__ SUMSQ5,
        const unsigned* __restrict__ MAXB, const unsigned* __restrict__ MINB,
        const float* __restrict__ g5, const float* __restrict__ b5, float* __restrict__ P)
{
  int o = blockIdx.x*256 + threadIdx.x;
  if (o>=2048) return;
  float m = SUM5[o]*(1.f/8192.f);
  float var = SUMSQ5[o]*(1.f/8192.f) - m*m;
  float sc = g5[o] * rsqrtf(var + 1e-5f);
  float sh = b5[o] - m*sc;
  for (int b=0;b<4;++b){
    float mx = fdec(MAXB[b*2048+o]);
    float mn = fdec(MINB[b*2048+o]);
    float v = (sc >= 0.f) ? fmaf(sc,mx,sh) : fmaf(sc,mn,sh);
    v = (v > 0.f) ? v : 0.2f*v;
    P[b*2048 + o] = v;
  }
}

// ---------------- small FC: Y(B,O) = W(O,Cin)*Z(B,Cin) + bias, one wave per o ----------------
__global__ __launch_bounds__(256) void k_fc(const float* __restrict__ W, const float* __restrict__ bias,
        const float* __restrict__ Z, int Cin, int O, float* __restrict__ Y)
{
  int o = blockIdx.x*4 + (threadIdx.x>>6);
  int lane = threadIdx.x & 63;
  if (o >= O) return;
  const float* wr = W + (size_t)o*Cin;
  float a0=0.f,a1=0.f,a2=0.f,a3=0.f;
  for (int c=lane;c<Cin;c+=64){
    float w = wr[c];
    a0 = fmaf(w, Z[c],        a0);
    a1 = fmaf(w, Z[Cin+c],    a1);
    a2 = fmaf(w, Z[2*Cin+c],  a2);
    a3 = fmaf(w, Z[3*Cin+c],  a3);
  }
  #pragma unroll
  for (int s=32;s;s>>=1){
    a0 += __shfl_down(a0,(unsigned)s); a1 += __shfl_down(a1,(unsigned)s);
    a2 += __shfl_down(a2,(unsigned)s); a3 += __shfl_down(a3,(unsigned)s);
  }
  if (lane==0){
    float bb = bias[o];
    Y[o]=a0+bb; Y[O+o]=a1+bb; Y[2*O+o]=a2+bb; Y[3*O+o]=a3+bb;
  }
}

// ---------------- BN over batch (4 samples) + relu ----------------
__global__ void k_bn4(const float* __restrict__ Y, const float* __restrict__ g, const float* __restrict__ bt,
                      int O, float* __restrict__ Z, int zstride, int zoff)
{
  int o = blockIdx.x*256 + threadIdx.x;
  if (o>=O) return;
  float v0=Y[o], v1=Y[O+o], v2=Y[2*O+o], v3=Y[3*O+o];
  float m = 0.25f*(v0+v1+v2+v3);
  float d0=v0-m, d1=v1-m, d2=v2-m, d3=v3-m;
  float var = 0.25f*(d0*d0+d1*d1+d2*d2+d3*d3);
  float sc = g[o] * rsqrtf(var + 1e-5f);
  float sh = bt[o] - m*sc;
  Z[0*zstride+zoff+o] = fmaxf(fmaf(sc,v0,sh), 0.f);
  Z[1*zstride+zoff+o] = fmaxf(fmaf(sc,v1,sh), 0.f);
  Z[2*zstride+zoff+o] = fmaxf(fmaf(sc,v2,sh), 0.f);
  Z[3*zstride+zoff+o] = fmaxf(fmaf(sc,v3,sh), 0.f);
}

__global__ void k_copy_p(const float* __restrict__ P, float* __restrict__ Z){
  int i = blockIdx.x*256 + threadIdx.x;   // < 4*2048
  int b = i>>11, o = i&2047;
  Z[b*4096 + 2048 + o] = P[i];
}

// ---------------- final: y8 = w8*z7 + wb8, tanh, fp32 out (4,400) ----------------
__global__ __launch_bounds__(256) void k_final(const float* __restrict__ W8, const float* __restrict__ wb8,
        const float* __restrict__ Z7, float* __restrict__ out)
{
  int o = blockIdx.x*4 + (threadIdx.x>>6);
  int lane = threadIdx.x & 63;
  if (o >= 400) return;
  const float* wr = W8 + (size_t)o*4096;
  float a0=0.f,a1=0.f,a2=0.f,a3=0.f;
  for (int c=lane;c<4096;c+=64){
    float w = wr[c];
    a0 = fmaf(w, Z7[c],        a0);
    a1 = fmaf(w, Z7[4096+c],   a1);
    a2 = fmaf(w, Z7[2*4096+c], a2);
    a3 = fmaf(w, Z7[3*4096+c], a3);
  }
  #pragma unroll
  for (int s=32;s;s>>=1){
    a0 += __shfl_down(a0,(unsigned)s); a1 += __shfl_down(a1,(unsigned)s);
    a2 += __shfl_down(a2,(unsigned)s); a3 += __shfl_down(a3,(unsigned)s);
  }
  if (lane==0){
    float bb = wb8[o];
    out[0*400+o] = tanhf(a0+bb);
    out[1*400+o] = tanhf(a1+bb);
    out[2*400+o] = tanhf(a2+bb);
    out[3*400+o] = tanhf(a3+bb);
  }
}

extern "C" void kernel_launch(void* const* d_in, const int* in_sizes, int n_in,
                              void* d_out, int out_size, void* d_ws, size_t ws_size,
                              hipStream_t stream)
{
  const float* x   = (const float*)d_in[0];
  const float* w_e[4]  = {(const float*)d_in[1], (const float*)d_in[4], (const float*)d_in[7], (const float*)d_in[10]};
  const float* g_e[4]  = {(const float*)d_in[2], (const float*)d_in[5], (const float*)d_in[8], (const float*)d_in[11]};
  const float* b_e[4]  = {(const float*)d_in[3], (const float*)d_in[6], (const float*)d_in[9], (const float*)d_in[12]};
  const float* w5  = (const float*)d_in[13];
  const float* g5  = (const float*)d_in[14];
  const float* b5  = (const float*)d_in[15];
  const float* w6  = (const float*)d_in[16];
  const float* wb6 = (const float*)d_in[17];
  const float* g6  = (const float*)d_in[18];
  const float* b6  = (const float*)d_in[19];
  const float* w7  = (const float*)d_in[20];
  const float* wb7 = (const float*)d_in[21];
  const float* g7  = (const float*)d_in[22];
  const float* b7  = (const float*)d_in[23];
  const float* w8  = (const float*)d_in[24];
  const float* wb8 = (const float*)d_in[25];

  float* WS = (float*)d_ws;
  float* H    = WS;                          // 7,888,896
  float* V    = WS + 7888896;                // 4,194,304
  float* U    = V  + 4194304;                // 4,194,304
  float* YMX  = U  + 4194304;                // 4,194,304
  float* YMN  = YMX+ 4194304;                // 4,194,304
  int*   IDX  = (int*)(YMN + 4194304);       //   163,840 ints
  float* X2   = (float*)(IDX + 163840);      //     8,192
  float* SUM  = X2 + 8192;                   //       512
  float* SUMSQ= SUM + 512;                   //       512
  float* SC   = SUMSQ + 512;                 //       512
  float* SH   = SC + 512;                    //       512
  float* SUM5 = SH + 512;                    //     2,048
  float* SUMSQ5 = SUM5 + 2048;               //     2,048
  unsigned* MAXB = (unsigned*)(SUMSQ5 + 2048); //   8,192
  unsigned* MINB = MAXB + 8192;              //     8,192
  float* P    = (float*)(MINB + 8192);       //     8,192
  float* Y6   = P + 8192;                    //     8,192
  float* Z    = Y6 + 8192;                   //    16,384
  float* Y7   = Z + 16384;                   //    16,384
  float* Z7   = Y7 + 16384;                  //    16,384
  // aliases (stage-disjoint lifetimes):
  _Float16* Hf  = (_Float16*)V;              // l5 operand, after edge stages
  _Float16* Wf  = (_Float16*)U;              // l5 operand
  // knn/edge split operands live in YMN (dead until k_gather overwrites);
  // Gram G1 lives in V (dead until k_vu_mfma writes it, after k_sel reads).
  _Float16* Xhi  = (_Float16*)YMN;                 // 4 MB
  _Float16* Xlo  = Xhi + (size_t)4*2048*256;       // 4 MB
  _Float16* Wsph = Xlo + (size_t)4*2048*256;       // 0.5 MB (max 1024x256)
  _Float16* Wspl = Wsph + 1024*256;                // 0.5 MB
  float* G0 = YMX;                           // per-batch Gram (16.8 MB each)
  float* G1 = V;

  k_convert<<<96,256,0,stream>>>(x, H);

  const int Cin_[4]  = {3,64,128,256};
  const int Cpad_[4] = {32,64,128,256};
  const int O_[4]    = {64,128,256,512};
  const int ioff_[4] = {0,3,67,195};
  const int ooff_[4] = {3,67,195,451};

  for (int l=0;l<4;++l){
    const float* Xl = H + (size_t)ioff_[l]*NPTS;
    int C = Cin_[l], Cpad = Cpad_[l], O = O_[l];
    k_norms<<<32,256,0,stream>>>(Xl, C, X2, SUM);
    dim3 gxs(32, (Cpad+63)/64, 4);
    k_xsplit<<<gxs,256,0,stream>>>(Xl, C, Cpad, Xhi, Xlo);
    k_wsplit<<<(2*O*Cpad+255)/256,256,0,stream>>>(w_e[l], C, Cpad, O, Wsph, Wspl);
    dim3 ggr(16,16,2);
    k_gram<<<ggr,256,0,stream>>>(Xhi, Xlo, Cpad, 0, G0, G1);
    dim3 gsl(512,2);
    k_sel<<<gsl,256,0,stream>>>(G0, G1, X2, 0, IDX);
    k_gram<<<ggr,256,0,stream>>>(Xhi, Xlo, Cpad, 2, G0, G1);
    k_sel<<<gsl,256,0,stream>>>(G0, G1, X2, 2, IDX);
    dim3 gvm(16, (2*O)/128, 4);
    k_vu_mfma<<<gvm,256,0,stream>>>(Xhi, Xlo, Wsph, Wspl, Cpad, O, V, U);
    if (O == 64)
      k_gather<64,1><<<1024,256,0,stream>>>(V, U, IDX, YMX, YMN, SUM, SUMSQ);
    else if (O == 128)
      k_gather<128,1><<<1024,256,0,stream>>>(V, U, IDX, YMX, YMN, SUM, SUMSQ);
    else if (O == 256)
      k_gather<128,2><<<2048,256,0,stream>>>(V, U, IDX, YMX, YMN, SUM, SUMSQ);
    else
      k_gather<128,4><<<4096,256,0,stream>>>(V, U, IDX, YMX, YMN, SUM, SUMSQ);
    k_finalize<<<2,256,0,stream>>>(SUM, SUMSQ, g_e[l], b_e[l], O, 1.f/163840.f, SC, SH);
    dim3 gap(32, O/64, 4);
    k_apply<<<gap,256,0,stream>>>(YMX, YMN, SC, SH, O, H + (size_t)ooff_[l]*NPTS);
  }

  // ---- layer 5 on MFMA ----
  dim3 gtr(32,16,4);
  k_h2f16<<<gtr,256,0,stream>>>(H, Hf);
  k_w5f16<<<(2048*KPAD+255)/256,256,0,stream>>>(w5, Wf, (unsigned*)SUM5);
  dim3 g5g(16,16,4);
  k_l5mfma<<<g5g,256,0,stream>>>(Wf, Hf, SUM5, SUMSQ5, MAXB, MINB);
  k_l5_final<<<8,256,0,stream>>>(SUM5, SUMSQ5, MAXB, MINB, g5, b5, P);

  k_fc<<<512,256,0,stream>>>(w6, wb6, P, 2048, 2048, Y6);
  k_bn4<<<8,256,0,stream>>>(Y6, g6, b6, 2048, Z, 4096, 0);
  k_copy_p<<<32,256,0,stream>>>(P, Z);
  k_fc<<<1024,256,0,stream>>>(w7, wb7, Z, 4096, 4096, Y7);
  k_bn4<<<16,256,0,stream>>>(Y7, g7, b7, 4096, Z7, 4096, 0);
  k_final<<<100,256,0,stream>>>(w8, wb8, Z7, (float*)d_out);
}

// Round 10
// 999.860 us; speedup vs baseline: 1.1023x; 1.0014x over previous
//
#include <hip/hip_runtime.h>
#include <float.h>
#include <math.h>

// DGCNN control-points pipeline, fp32 compute; MFMA (f16 hi/lo split) for the
// knn Gram matrix, edge-conv projection, and f16-MFMA for the layer-5 GEMM.
//
// Edge conv decomposition: y[b,o,n,k] = W·[nbr-ctr; ctr]
//   = v[b, idx(n,k), o] + u[b,n,o]   with v = Wd·x, u = (Wc-Wd)·x
// BN is batch-stats. knn: G = X^T X via mfma f16 hi/lo split;
// d = x2[n]+x2[m]-2G; per-wave register top-20 (exact lax.top_k order).
// Layer-5 (2048x963x8192) on matrix cores, BN-stat/max fused via atomics.
//
// R1: k_gather o-chunked + XCD-affinity, nontemporal streams (103us -> gone).
// R2: global_load_lds single-buffered -> regressed (exposed latency).
// R3: 2-phase dbuf w/ __syncthreads: l5 95->80us.
// R4: counted-vmcnt raw-barrier pipeline. l5 ~77us. 1075->1065.
// R5: k_vu -> MFMA (k_vu_mfma). 1065->1001us.
// R6: triangular gram REGRESSED (latency-bound blocks; mirror scatter).
// R7: XCD o-chunking REGRESSED (FETCH 39->100MB). Reverted.
// R8: l5 triple-buffer single-barrier: NEUTRAL (77us) -> barrier count not
//     the marginal cost. Kept (fewer instructions).
// R9: kill the 4.06M LDS bank-conflict cycles on all 3 MFMA GEMMs.
//     Fragment reads at row-stride 64B put 8 lanes/bank per 16-lane phase
//     (8-way). Fix per guide rule 21 (both-sides-or-neither with
//     global_load_lds): LDS dest stays linear; global SOURCE chunk is
//     pre-swizzled kc^( (row>>1)&3 ), and reads use quad^((col>>1)&3).
//     Bank-starts spread 8-wide -> 2-way (free). Bitwise-identical data.

#define NPTS 2048
#define BATCH 4
#define KNN 20
#define CH_H 963
#define KPAD 992              // 963 padded to 31*32
#define HSTRIDE (CH_H*NPTS)   // per-batch element stride of concat buffer H

typedef _Float16 half8 __attribute__((ext_vector_type(8)));
typedef float f32x4 __attribute__((ext_vector_type(4)));

// direct global->LDS 16B DMA; lds dest is wave-uniform base + lane*16
typedef const __attribute__((address_space(1))) unsigned int* gas_p;
typedef __attribute__((address_space(3))) unsigned int* las_p;
__device__ __forceinline__ void gl_lds16(const void* g, void* l){
  __builtin_amdgcn_global_load_lds((gas_p)g, (las_p)l, 16, 0, 0);
}

// order-preserving float<->uint for atomicMax/Min
__device__ __forceinline__ unsigned fenc(float x){
  unsigned u = __float_as_uint(x);
  return (u & 0x80000000u) ? ~u : (u | 0x80000000u);
}
__device__ __forceinline__ float fdec(unsigned u){
  u = (u & 0x80000000u) ? (u ^ 0x80000000u) : ~u;
  return __uint_as_float(u);
}

// ---------------- copy input x (B,3,N) -> H rows [0,3) ----------------
__global__ void k_convert(const float* __restrict__ x, float* __restrict__ H){
  int i = blockIdx.x*256 + threadIdx.x;
  if (i >= BATCH*3*NPTS) return;
  int b = i / (3*NPTS); int r = i % (3*NPTS);
  H[(size_t)b*HSTRIDE + r] = x[i];
}

// ---------------- per-point squared norms (+ zero SUM/SUMSQ for this layer) ----------------
__global__ void k_norms(const float* __restrict__ X, int C, float* __restrict__ X2,
                        float* __restrict__ SUMZ){
  int i = blockIdx.x*256 + threadIdx.x;     // b*2048+n
  if (i < 1024) SUMZ[i] = 0.f;              // SUM[512] ++ SUMSQ[512] contiguous
  int b = i >> 11, n = i & 2047;
  const float* Xb = X + (size_t)b*HSTRIDE + n;
  float s = 0.f;
  for (int c=0;c<C;++c){ float v = Xb[(size_t)c*NPTS]; s = fmaf(v,v,s); }
  X2[i] = s;
}

// ---------------- X (b,c,n) fp32 -> Xhi/Xlo (b,n,Cpad) f16 split ----------------
__global__ __launch_bounds__(256) void k_xsplit(const float* __restrict__ X, int C, int Cpad,
        _Float16* __restrict__ Xhi, _Float16* __restrict__ Xlo)
{
  __shared__ float t[64][65];
  int b = blockIdx.z;
  int n0 = blockIdx.x*64, c0 = blockIdx.y*64;
  int tid = threadIdx.x; int l = tid & 63, m = tid >> 6;
  for (int cc = m; cc < 64; cc += 4){
    int c = c0 + cc;
    t[cc][l] = (c < C) ? X[(size_t)b*HSTRIDE + (size_t)c*NPTS + n0 + l] : 0.f;
  }
  __syncthreads();
  for (int nn = m; nn < 64; nn += 4){
    int c = c0 + l;
    if (c < Cpad){
      float v = t[l][nn];
      _Float16 h = (_Float16)v;
      size_t o = ((size_t)(b<<11)+n0+nn)*Cpad + c;
      Xhi[o] = h;
      Xlo[o] = (_Float16)(v - (float)h);
    }
  }
}

// ---------------- W (O,2C) fp32 -> Wcat=[Wd; Wc-Wd] (2O,Cpad) f16 hi/lo ----------------
__global__ void k_wsplit(const float* __restrict__ W, int C, int Cpad, int O,
        _Float16* __restrict__ Wh, _Float16* __restrict__ Wl){
  int i = blockIdx.x*256 + threadIdx.x;
  if (i >= 2*O*Cpad) return;
  int op = i / Cpad, c = i - op*Cpad;
  float v = 0.f;
  if (c < C){
    const float* wr = W + (size_t)(op < O ? op : op - O)*(2*C);
    v = (op < O) ? wr[c] : (wr[C+c] - wr[c]);
  }
  _Float16 h = (_Float16)v;
  Wh[i] = h; Wl[i] = (_Float16)(v - (float)h);
}

// ---------------- Gram via MFMA: G[n][m] = sum_c X[n][c]*X[m][c] ----------------
// 128x128 tile, 4 waves x (64x64); 3 MFMAs (hh,hl,lh) per fragment pair.
// Counted-vmcnt raw-barrier pipeline, depth-2 prefetch.
// R9: bank-conflict swizzle (source-chunk XOR + read-chunk XOR).
__global__ __launch_bounds__(256) void k_gram(const _Float16* __restrict__ Xhi,
        const _Float16* __restrict__ Xlo, int Cpad, int bbase,
        float* __restrict__ G0, float* __restrict__ G1)
{
  __shared__ __attribute__((aligned(128))) half8 AsH[2][128][4];
  __shared__ __attribute__((aligned(128))) half8 AsL[2][128][4];
  __shared__ __attribute__((aligned(128))) half8 BsH[2][128][4];
  __shared__ __attribute__((aligned(128))) half8 BsL[2][128][4];
  int bl = blockIdx.z;
  int b  = bbase + bl;
  float* G = bl ? G1 : G0;
  const _Float16* Hb = Xhi + (size_t)(b<<11)*Cpad;
  const _Float16* Lb = Xlo + (size_t)(b<<11)*Cpad;
  int m0 = blockIdx.x*128, n0 = blockIdx.y*128;
  int tid = threadIdx.x;
  int w = tid>>6, lane = tid&63;
  int wm = w>>1, wn = w&1;
  int quad = lane>>4, col = lane&15;
  int wbase = w*128;                    // staging slice base (in cid units)
  f32x4 acc[4][4];
  #pragma unroll
  for (int a=0;a<4;++a)
    #pragma unroll
    for (int c2=0;c2<4;++c2) acc[a][c2] = (f32x4){0.f,0.f,0.f,0.f};

  auto stageg = [&](int buf, int k0){
    #pragma unroll
    for (int s=0;s<2;++s){
      int cid = wbase + s*64 + lane;
      int row = cid>>2, kc = cid&3;
      int kcg = kc ^ ((row>>1)&3);      // R9 source-chunk swizzle
      size_t ao = (size_t)(n0+row)*Cpad + k0 + kcg*8;
      size_t bo = (size_t)(m0+row)*Cpad + k0 + kcg*8;
      int lo = (wbase + s*64)*16;       // wave-uniform LDS byte base (linear)
      gl_lds16(Hb + ao, (char*)&AsH[buf][0][0] + lo);
      gl_lds16(Lb + ao, (char*)&AsL[buf][0][0] + lo);
      gl_lds16(Hb + bo, (char*)&BsH[buf][0][0] + lo);
      gl_lds16(Lb + bo, (char*)&BsL[buf][0][0] + lo);
    }
  };

  int qs = quad ^ ((col>>1)&3);         // R9 read-chunk swizzle (rows base%16==0)
  int NT = Cpad >> 5;
  stageg(0, 0);                         // 8 loads in flight
  if (NT > 1) stageg(1, 32);            // 16 in flight
  for (int kt=0; kt<NT; ++kt){
    int buf = kt & 1;
    // wait only THIS buf's 8 loads; next buf's 8 stay in flight (T4)
    if (kt+1 < NT) asm volatile("s_waitcnt vmcnt(8)" ::: "memory");
    else           asm volatile("s_waitcnt vmcnt(0)" ::: "memory");
    __builtin_amdgcn_s_barrier();       // RAW: all waves' loads landed
    __builtin_amdgcn_sched_barrier(0);
    half8 ah[4], al[4], bh[4], blo[4];
    #pragma unroll
    for (int mt=0;mt<4;++mt){ ah[mt] = AsH[buf][wm*64 + mt*16 + col][qs];
                              al[mt] = AsL[buf][wm*64 + mt*16 + col][qs]; }
    #pragma unroll
    for (int nt=0;nt<4;++nt){ bh[nt] = BsH[buf][wn*64 + nt*16 + col][qs];
                              blo[nt] = BsL[buf][wn*64 + nt*16 + col][qs]; }
    #pragma unroll
    for (int mt=0;mt<4;++mt)
      #pragma unroll
      for (int nt=0;nt<4;++nt){
        acc[mt][nt] = __builtin_amdgcn_mfma_f32_16x16x32_f16(ah[mt], bh[nt], acc[mt][nt], 0, 0, 0);
        acc[mt][nt] = __builtin_amdgcn_mfma_f32_16x16x32_f16(ah[mt], blo[nt], acc[mt][nt], 0, 0, 0);
        acc[mt][nt] = __builtin_amdgcn_mfma_f32_16x16x32_f16(al[mt], bh[nt], acc[mt][nt], 0, 0, 0);
      }
    __builtin_amdgcn_sched_barrier(0);
    __builtin_amdgcn_s_barrier();       // WAR: all waves done reading buf
    if (kt+2 < NT) stageg(buf, (kt+2)<<5);  // overwrite buf for tile kt+2
  }
  // C/D layout: col(m within 16)=lane&15, row(n within 16)=quad*4+r
  #pragma unroll
  for (int mt=0;mt<4;++mt){
    #pragma unroll
    for (int r=0;r<4;++r){
      int n = n0 + wm*64 + mt*16 + quad*4 + r;
      #pragma unroll
      for (int nt=0;nt<4;++nt){
        int m = m0 + wn*64 + nt*16 + col;
        G[(size_t)n*2048 + m] = acc[mt][nt][r];
      }
    }
  }
}

// ---------------- edge-conv projection on MFMA: Y(n,o') = X(n,:)·Wcat(o',:) ----------------
// o' in [0,2O): rows [0,O)=Wd -> V, rows [O,2O)=Wc-Wd -> U.
// R9: bank-conflict swizzle as in k_gram.
__global__ __launch_bounds__(256) void k_vu_mfma(const _Float16* __restrict__ Xh,
        const _Float16* __restrict__ Xl, const _Float16* __restrict__ Wh,
        const _Float16* __restrict__ Wl, int Cpad, int O,
        float* __restrict__ V, float* __restrict__ U)
{
  __shared__ __attribute__((aligned(128))) half8 AsH[2][128][4];
  __shared__ __attribute__((aligned(128))) half8 AsL[2][128][4];
  __shared__ __attribute__((aligned(128))) half8 BsH[2][128][4];
  __shared__ __attribute__((aligned(128))) half8 BsL[2][128][4];
  int b = blockIdx.z;
  const _Float16* Hb = Xh + (size_t)(b<<11)*Cpad;
  const _Float16* Lb = Xl + (size_t)(b<<11)*Cpad;
  int n0 = blockIdx.x*128, o0 = blockIdx.y*128;   // o0 in o' space
  int tid = threadIdx.x;
  int w = tid>>6, lane = tid&63;
  int wm = w>>1, wn = w&1;
  int quad = lane>>4, col = lane&15;
  int wbase = w*128;
  f32x4 acc[4][4];
  #pragma unroll
  for (int i=0;i<4;++i)
    #pragma unroll
    for (int j=0;j<4;++j) acc[i][j] = (f32x4){0.f,0.f,0.f,0.f};

  auto stagev = [&](int buf, int k0){
    #pragma unroll
    for (int i=0;i<2;++i){
      int cid = wbase + i*64 + lane;
      int row = cid>>2, kc = cid&3;
      int kcg = kc ^ ((row>>1)&3);      // R9 source-chunk swizzle
      size_t ao = (size_t)(n0+row)*Cpad + k0 + kcg*8;
      size_t bo = (size_t)(o0+row)*Cpad + k0 + kcg*8;
      int lo = (wbase + i*64)*16;
      gl_lds16(Hb + ao, (char*)&AsH[buf][0][0] + lo);
      gl_lds16(Lb + ao, (char*)&AsL[buf][0][0] + lo);
      gl_lds16(Wh + bo, (char*)&BsH[buf][0][0] + lo);
      gl_lds16(Wl + bo, (char*)&BsL[buf][0][0] + lo);
    }
  };

  int qs = quad ^ ((col>>1)&3);         // R9 read-chunk swizzle
  int NT = Cpad >> 5;
  stagev(0, 0);
  if (NT > 1) stagev(1, 32);
  for (int kt=0; kt<NT; ++kt){
    int buf = kt & 1;
    if (kt+1 < NT) asm volatile("s_waitcnt vmcnt(8)" ::: "memory");
    else           asm volatile("s_waitcnt vmcnt(0)" ::: "memory");
    __builtin_amdgcn_s_barrier();
    __builtin_amdgcn_sched_barrier(0);
    half8 ah[4], al[4], bh[4], blo[4];
    #pragma unroll
    for (int mt=0;mt<4;++mt){ ah[mt] = AsH[buf][wm*64 + mt*16 + col][qs];
                              al[mt] = AsL[buf][wm*64 + mt*16 + col][qs]; }
    #pragma unroll
    for (int nt=0;nt<4;++nt){ bh[nt] = BsH[buf][wn*64 + nt*16 + col][qs];
                              blo[nt] = BsL[buf][wn*64 + nt*16 + col][qs]; }
    #pragma unroll
    for (int mt=0;mt<4;++mt)
      #pragma unroll
      for (int nt=0;nt<4;++nt){
        acc[mt][nt] = __builtin_amdgcn_mfma_f32_16x16x32_f16(ah[mt], bh[nt], acc[mt][nt], 0, 0, 0);
        acc[mt][nt] = __builtin_amdgcn_mfma_f32_16x16x32_f16(ah[mt], blo[nt], acc[mt][nt], 0, 0, 0);
        acc[mt][nt] = __builtin_amdgcn_mfma_f32_16x16x32_f16(al[mt], bh[nt], acc[mt][nt], 0, 0, 0);
      }
    __builtin_amdgcn_sched_barrier(0);
    __builtin_amdgcn_s_barrier();
    if (kt+2 < NT) stagev(buf, (kt+2)<<5);
  }
  // epilogue: (n, o') -> V if o'<O else U
  #pragma unroll
  for (int mt=0;mt<4;++mt){
    #pragma unroll
    for (int r=0;r<4;++r){
      int n = n0 + wm*64 + mt*16 + quad*4 + r;
      size_t R = (size_t)(b<<11) + n;
      #pragma unroll
      for (int nt=0;nt<4;++nt){
        int op = o0 + wn*64 + nt*16 + col;
        float y = acc[mt][nt][r];
        if (op < O) V[R*O + op] = y;
        else        U[R*O + op - O] = y;
      }
    }
  }
}

// ---------------- top-20 selection from Gram row ----------------
#define KNN_CH(OPC) OPC(0) OPC(1) OPC(2) OPC(3) OPC(4) OPC(5) OPC(6) OPC(7)
#define DECL_CH(ch) float d##ch##_0,d##ch##_1,d##ch##_2,d##ch##_3;
#define LOADG_CH(ch) { float4 g = *(const float4*)(grow + (ch)*256 + base); \
  float4 xm = *(const float4*)(x2b + (ch)*256 + base); \
  d##ch##_0 = x2n + xm.x - 2.f*g.x; d##ch##_1 = x2n + xm.y - 2.f*g.y; \
  d##ch##_2 = x2n + xm.z - 2.f*g.z; d##ch##_3 = x2n + xm.w - 2.f*g.w; }
#define DECL_G(ch) float gv##ch; int gm##ch;
// strict < in ascending slot order -> smallest idx among exact ties
#define MKCH(ch) { gv##ch = d##ch##_0; gm##ch = (ch)*256 + base; \
  if (d##ch##_1 < gv##ch){ gv##ch = d##ch##_1; gm##ch = (ch)*256 + base + 1; } \
  if (d##ch##_2 < gv##ch){ gv##ch = d##ch##_2; gm##ch = (ch)*256 + base + 2; } \
  if (d##ch##_3 < gv##ch){ gv##ch = d##ch##_3; gm##ch = (ch)*256 + base + 3; } }
#define REMCASE(ch) case ch: { \
  if (own){ if (cp==0) d##ch##_0 = FLT_MAX; else if (cp==1) d##ch##_1 = FLT_MAX; \
            else if (cp==2) d##ch##_2 = FLT_MAX; else d##ch##_3 = FLT_MAX; } \
  MKCH(ch) } break;

__global__ __launch_bounds__(256,4) void k_sel(const float* __restrict__ G0,
        const float* __restrict__ G1, const float* __restrict__ X2,
        int bbase, int* __restrict__ IDX)
{
  int tid = threadIdx.x;
  int w = tid >> 6, lane = tid & 63;
  int n = blockIdx.x*4 + w;
  int b = bbase + blockIdx.y;
  const float* grow = (blockIdx.y ? G1 : G0) + (size_t)n*2048;
  const float* x2b  = X2 + (b<<11);
  float x2n = x2b[n];
  int base = lane << 2;
  KNN_CH(DECL_CH)
  KNN_CH(LOADG_CH)
  KNN_CH(DECL_G)
  KNN_CH(MKCH)
  int* op = IDX + ((size_t)(b<<11)+n)*KNN;
  for (int it=0; it<KNN; ++it){
    float v = fminf(fminf(fminf(gv0,gv1),fminf(gv2,gv3)),
                    fminf(fminf(gv4,gv5),fminf(gv6,gv7)));
    #pragma unroll
    for (int s=1; s<64; s<<=1) v = fminf(v, __shfl_xor(v, s));
    int mc = 0x7fffffff;
    mc = (gv7==v) ? gm7 : mc;
    mc = (gv6==v) ? gm6 : mc;
    mc = (gv5==v) ? gm5 : mc;
    mc = (gv4==v) ? gm4 : mc;
    mc = (gv3==v) ? gm3 : mc;
    mc = (gv2==v) ? gm2 : mc;
    mc = (gv1==v) ? gm1 : mc;
    mc = (gv0==v) ? gm0 : mc;
    int m = mc;
    #pragma unroll
    for (int s=1; s<64; s<<=1) m = min(m, __shfl_xor(m, s));
    if (lane==0) op[it] = m;
    int sm = __builtin_amdgcn_readfirstlane(m);
    bool own = (lane == ((sm>>2)&63));
    int cp = sm & 3;
    switch (sm >> 8){ KNN_CH(REMCASE) }
  }
}

// ---------------- single gather pass: ymax/ymin per (b,n,o) + channel sum/sumsq ----------------
template<int OC, int CHN>
__global__ __launch_bounds__(256) void k_gather(const float* __restrict__ V,
        const float* __restrict__ U, const int* __restrict__ IDX,
        float* __restrict__ YMX, float* __restrict__ YMN,
        float* __restrict__ SUM, float* __restrict__ SUMSQ)
{
  constexpr int O = OC*CHN;
  constexpr int NT = 8;
  constexpr int NSTEP = 256/OC;       // threads sharing one o column
  __shared__ int sidx[NT*KNN];
  __shared__ float rs[256], rq[256];
  int bid = blockIdx.x;
  int xcd  = bid & 7;                 // HW round-robin wg->XCD (learn_hip m09)
  int b    = xcd >> 1;
  int half = xcd & 1;
  int r    = bid >> 3;
  int ngrp, chunk;
  if (CHN == 1){ ngrp = (half<<7) | r; chunk = 0; }        // r in [0,128)
  else         { ngrp = r & 255; chunk = half*(CHN/2) + (r>>8); }
  int n0 = ngrp * NT;
  int tid = threadIdx.x;
  for (int l = tid; l < NT*KNN; l += 256)
    sidx[l] = IDX[((size_t)(b<<11)+n0)*KNN + l];
  __syncthreads();
  int o  = chunk*OC + (tid & (OC-1));
  int ns = tid / OC;
  const float* Vb = V + (size_t)(b<<11)*O + o;
  float s = 0.f, q = 0.f;
  #pragma unroll
  for (int i = 0; i < NT/NSTEP; ++i){
    int nn = ns + i*NSTEP;
    int n = n0 + nn;
    size_t ub = ((size_t)(b<<11)+n)*O + o;
    float sv = 0.f, sv2 = 0.f, mx = -FLT_MAX, mn = FLT_MAX;
    #pragma unroll
    for (int k=0;k<KNN;++k){
      int m = sidx[nn*KNN+k];
      float v = Vb[(size_t)m*O];
      mx = fmaxf(mx,v); mn = fminf(mn,v);
      sv += v; sv2 = fmaf(v,v,sv2);
    }
    float u = __builtin_nontemporal_load(U + ub);
    __builtin_nontemporal_store(mx + u, YMX + ub);
    __builtin_nontemporal_store(mn + u, YMN + ub);
    s += sv + (float)KNN * u;
    q += sv2 + 2.f*u*sv + (float)KNN*u*u;
  }
  rs[tid] = s; rq[tid] = q;
  __syncthreads();
  if (tid < OC){
    #pragma unroll
    for (int t=1; t<NSTEP; ++t){ s += rs[tid + t*OC]; q += rq[tid + t*OC]; }
    atomicAdd(&SUM[o], s);
    atomicAdd(&SUMSQ[o], q);
  }
}

__global__ void k_finalize(const float* __restrict__ SUM, const float* __restrict__ SUMSQ,
        const float* __restrict__ g, const float* __restrict__ bt,
        int O, float invM, float* __restrict__ SC, float* __restrict__ SH){
  int o = blockIdx.x*256 + threadIdx.x;
  if (o>=O) return;
  float m = SUM[o]*invM;
  float var = SUMSQ[o]*invM - m*m;
  float sc = g[o] * rsqrtf(var + 1e-5f);
  SC[o]=sc; SH[o] = bt[o] - m*sc;
}

// ---------------- apply BN + lrelu to recorded extrema; transpose (b,n,o)->(b,o,n) ----------------
__global__ __launch_bounds__(256) void k_apply(const float* __restrict__ YMX, const float* __restrict__ YMN,
        const float* __restrict__ SC, const float* __restrict__ SH,
        int O, float* __restrict__ OUT)
{
  __shared__ float t[64][65];
  int b = blockIdx.z;
  int o0 = blockIdx.y*64, n0 = blockIdx.x*64;
  int tid = threadIdx.x;
  int lo = tid & 63, ln = tid >> 6;
  float sc = SC[o0+lo], sh = SH[o0+lo];
  for (int nn = ln; nn < 64; nn += 4){
    size_t idx = ((size_t)(b<<11)+n0+nn)*O + o0 + lo;
    float v = (sc >= 0.f) ? YMX[idx] : YMN[idx];
    float y = fmaf(sc, v, sh);
    y = (y > 0.f) ? y : 0.2f*y;
    t[lo][nn] = y;
  }
  __syncthreads();
  for (int oo = ln; oo < 64; oo += 4){
    OUT[(size_t)b*HSTRIDE + (size_t)(o0+oo)*NPTS + n0 + lo] = t[oo][lo];
  }
}

// ---------------- transpose H (b,c,n) fp32 -> Hf16 (b,n,KPAD) f16, zero-pad c>=963 ----------------
__global__ __launch_bounds__(256) void k_h2f16(const float* __restrict__ H, _Float16* __restrict__ Hf){
  __shared__ float t[64][65];
  int b = blockIdx.z;
  int n0 = blockIdx.x*64, c0 = blockIdx.y*64;
  int tid = threadIdx.x; int l = tid & 63, m = tid >> 6;
  for (int cc = m; cc < 64; cc += 4){
    int c = c0 + cc;
    t[cc][l] = (c < CH_H) ? H[(size_t)b*HSTRIDE + (size_t)c*NPTS + n0 + l] : 0.f;
  }
  __syncthreads();
  for (int nn = m; nn < 64; nn += 4){
    int c = c0 + l;
    if (c < KPAD)
      Hf[((size_t)(b<<11)+n0+nn)*KPAD + c] = (_Float16)t[l][nn];
  }
}

// ---------------- w5 -> f16 (+ zero l5 reduction buffers) ----------------
__global__ void k_w5f16(const float* __restrict__ w5, _Float16* __restrict__ Wf,
                        unsigned* __restrict__ z){
  int i = blockIdx.x*256 + threadIdx.x;
  if (i < 12288) z[i] = 0u;                 // SUM5,SUMSQ5,MAXB
  else if (i < 20480) z[i] = 0xFFFFFFFFu;   // MINB
  if (i >= 2048*KPAD) return;
  int o = i / KPAD, c = i - o*KPAD;
  Wf[i] = (c < CH_H) ? (_Float16)w5[(size_t)o*CH_H + c] : (_Float16)0.f;
}

// ---------------- layer-5 GEMM on MFMA, fused BN-stat/max epilogue ----------------
// R8: triple-buffered LDS, depth-2 prefetch, one barrier per K-iter.
// R9: bank-conflict swizzle (source-chunk XOR + read-chunk XOR).
__global__ __launch_bounds__(256) void k_l5mfma(const _Float16* __restrict__ Wf,
        const _Float16* __restrict__ Hf,
        float* __restrict__ SUM5, float* __restrict__ SUMSQ5,
        unsigned* __restrict__ MAXB, unsigned* __restrict__ MINB)
{
  __shared__ __attribute__((aligned(128))) half8 As[3][128][4];  // 24 KB
  __shared__ __attribute__((aligned(128))) half8 Bs[3][128][4];  // 24 KB
  int b  = blockIdx.z;
  int n0 = blockIdx.x*128, o0 = blockIdx.y*128;
  int tid = threadIdx.x;
  int w = tid>>6, lane = tid&63;
  int wm = w>>1, wn = w&1;          // wave grid 2x2
  int quad = lane>>4, col = lane&15;
  int wbase = w*128;                // staging slice base (in cid units)
  f32x4 acc[4][4];
  #pragma unroll
  for (int i=0;i<4;++i)
    #pragma unroll
    for (int j=0;j<4;++j) acc[i][j] = (f32x4){0.f,0.f,0.f,0.f};

  auto stage5 = [&](int buf, int k0){
    #pragma unroll
    for (int i=0;i<2;++i){
      int cid = wbase + i*64 + lane;
      int row = cid>>2, kc = cid&3;
      int kcg = kc ^ ((row>>1)&3);  // R9 source-chunk swizzle
      int lo = (wbase + i*64)*16;   // wave-uniform LDS byte base (linear)
      gl_lds16(Wf + (size_t)(o0+row)*KPAD + k0 + kcg*8, (char*)&As[buf][0][0] + lo);
      gl_lds16(Hf + ((size_t)(b<<11)+n0+row)*KPAD + k0 + kcg*8, (char*)&Bs[buf][0][0] + lo);
    }
  };

  int qs = quad ^ ((col>>1)&3);     // R9 read-chunk swizzle
  const int NT = KPAD/32;           // 31
  stage5(0, 0);                     // 4 loads in flight
  stage5(1, 32);                    // 8 in flight
  int bcur = 0;                     // rotating buffer index
  for (int kt=0; kt<NT; ++kt){
    int buf = bcur;
    // wait only THIS buf's 4 loads; next buf's 4 stay in flight (T4)
    if (kt+1 < NT) asm volatile("s_waitcnt vmcnt(4)" ::: "memory");
    else           asm volatile("s_waitcnt vmcnt(0)" ::: "memory");
    __builtin_amdgcn_s_barrier();   // buf_kt ready; buf_{kt-1} fully consumed
    __builtin_amdgcn_sched_barrier(0);
    if (kt+2 < NT){
      int nb = buf + 2; if (nb >= 3) nb -= 3;
      stage5(nb, (kt+2)*32);
    }
    half8 af[4], bf[4];
    #pragma unroll
    for (int mt=0;mt<4;++mt) af[mt] = As[buf][wm*64 + mt*16 + col][qs];
    #pragma unroll
    for (int nt=0;nt<4;++nt) bf[nt] = Bs[buf][wn*64 + nt*16 + col][qs];
    #pragma unroll
    for (int mt=0;mt<4;++mt)
      #pragma unroll
      for (int nt=0;nt<4;++nt)
        acc[mt][nt] = __builtin_amdgcn_mfma_f32_16x16x32_f16(af[mt], bf[nt], acc[mt][nt], 0, 0, 0);
    __builtin_amdgcn_sched_barrier(0);
    bcur = bcur + 1; if (bcur == 3) bcur = 0;
  }
  // epilogue: C/D layout col(n)=lane&15, row(o)=quad*4+reg
  #pragma unroll
  for (int mt=0;mt<4;++mt){
    #pragma unroll
    for (int r=0;r<4;++r){
      float s=0.f, q=0.f, mx=-FLT_MAX, mn=FLT_MAX;
      #pragma unroll
      for (int nt=0;nt<4;++nt){
        float y = acc[mt][nt][r];
        s += y; q = fmaf(y,y,q);
        mx = fmaxf(mx,y); mn = fminf(mn,y);
      }
      #pragma unroll
      for (int d=8; d; d>>=1){
        s += __shfl_down(s,(unsigned)d,16);
        q += __shfl_down(q,(unsigned)d,16);
        mx = fmaxf(mx,__shfl_down(mx,(unsigned)d,16));
        mn = fminf(mn,__shfl_down(mn,(unsigned)d,16));
      }
      if (col==0){
        int o = o0 + wm*64 + mt*16 + quad*4 + r;
        atomicAdd(&SUM5[o], s);
        atomicAdd(&SUMSQ5[o], q);
        atomicMax(&MAXB[(b<<11)+o], fenc(mx));
        atomicMin(&MINB[(b<<11)+o], fenc(mn));
      }
    }
  }
}

// ---------------- layer-5 finalize: BN + leaky_relu + max over n -> P (B,2048) ----------------
__global__ void k_l5_final(const float* __restrict__ SUM5, const float* __restrict__ SUMSQ5,
        const unsigned* __restrict__ MAXB, const unsigned* __restrict__ MINB,
        const float* __restrict__ g5, const float* __restrict__ b5, float* __restrict__ P)
{
  int o = blockIdx.x*256 + threadIdx.x;
  if (o>=2048) return;
  float m = SUM5[o]*(1.f/8192.f);
  float var = SUMSQ5[o]*(1.f/8192.f) - m*m;
  float sc = g5[o] * rsqrtf(var + 1e-5f);
  float sh = b5[o] - m*sc;
  for (int b=0;b<4;++b){
    float mx = fdec(MAXB[b*2048+o]);
    float mn = fdec(MINB[b*2048+o]);
    float v = (sc >= 0.f) ? fmaf(sc,mx,sh) : fmaf(sc,mn,sh);
    v = (v > 0.f) ? v : 0.2f*v;
    P[b*2048 + o] = v;
  }
}

// ---------------- small FC: Y(B,O) = W(O,Cin)*Z(B,Cin) + bias, one wave per o ----------------
__global__ __launch_bounds__(256) void k_fc(const float* __restrict__ W, const float* __restrict__ bias,
        const float* __restrict__ Z, int Cin, int O, float* __restrict__ Y)
{
  int o = blockIdx.x*4 + (threadIdx.x>>6);
  int lane = threadIdx.x & 63;
  if (o >= O) return;
  const float* wr = W + (size_t)o*Cin;
  float a0=0.f,a1=0.f,a2=0.f,a3=0.f;
  for (int c=lane;c<Cin;c+=64){
    float w = wr[c];
    a0 = fmaf(w, Z[c],        a0);
    a1 = fmaf(w, Z[Cin+c],    a1);
    a2 = fmaf(w, Z[2*Cin+c],  a2);
    a3 = fmaf(w, Z[3*Cin+c],  a3);
  }
  #pragma unroll
  for (int s=32;s;s>>=1){
    a0 += __shfl_down(a0,(unsigned)s); a1 += __shfl_down(a1,(unsigned)s);
    a2 += __shfl_down(a2,(unsigned)s); a3 += __shfl_down(a3,(unsigned)s);
  }
  if (lane==0){
    float bb = bias[o];
    Y[o]=a0+bb; Y[O+o]=a1+bb; Y[2*O+o]=a2+bb; Y[3*O+o]=a3+bb;
  }
}

// ---------------- BN over batch (4 samples) + relu ----------------
__global__ void k_bn4(const float* __restrict__ Y, const float* __restrict__ g, const float* __restrict__ bt,
                      int O, float* __restrict__ Z, int zstride, int zoff)
{
  int o = blockIdx.x*256 + threadIdx.x;
  if (o>=O) return;
  float v0=Y[o], v1=Y[O+o], v2=Y[2*O+o], v3=Y[3*O+o];
  float m = 0.25f*(v0+v1+v2+v3);
  float d0=v0-m, d1=v1-m, d2=v2-m, d3=v3-m;
  float var = 0.25f*(d0*d0+d1*d1+d2*d2+d3*d3);
  float sc = g[o] * rsqrtf(var + 1e-5f);
  float sh = bt[o] - m*sc;
  Z[0*zstride+zoff+o] = fmaxf(fmaf(sc,v0,sh), 0.f);
  Z[1*zstride+zoff+o] = fmaxf(fmaf(sc,v1,sh), 0.f);
  Z[2*zstride+zoff+o] = fmaxf(fmaf(sc,v2,sh), 0.f);
  Z[3*zstride+zoff+o] = fmaxf(fmaf(sc,v3,sh), 0.f);
}

__global__ void k_copy_p(const float* __restrict__ P, float* __restrict__ Z){
  int i = blockIdx.x*256 + threadIdx.x;   // < 4*2048
  int b = i>>11, o = i&2047;
  Z[b*4096 + 2048 + o] = P[i];
}

// ---------------- final: y8 = w8*z7 + wb8, tanh, fp32 out (4,400) ----------------
__global__ __launch_bounds__(256) void k_final(const float* __restrict__ W8, const float* __restrict__ wb8,
        const float* __restrict__ Z7, float* __restrict__ out)
{
  int o = blockIdx.x*4 + (threadIdx.x>>6);
  int lane = threadIdx.x & 63;
  if (o >= 400) return;
  const float* wr = W8 + (size_t)o*4096;
  float a0=0.f,a1=0.f,a2=0.f,a3=0.f;
  for (int c=lane;c<4096;c+=64){
    float w = wr[c];
    a0 = fmaf(w, Z7[c],        a0);
    a1 = fmaf(w, Z7[4096+c],   a1);
    a2 = fmaf(w, Z7[2*4096+c], a2);
    a3 = fmaf(w, Z7[3*4096+c], a3);
  }
  #pragma unroll
  for (int s=32;s;s>>=1){
    a0 += __shfl_down(a0,(unsigned)s); a1 += __shfl_down(a1,(unsigned)s);
    a2 += __shfl_down(a2,(unsigned)s); a3 += __shfl_down(a3,(unsigned)s);
  }
  if (lane==0){
    float bb = wb8[o];
    out[0*400+o] = tanhf(a0+bb);
    out[1*400+o] = tanhf(a1+bb);
    out[2*400+o] = tanhf(a2+bb);
    out[3*400+o] = tanhf(a3+bb);
  }
}

extern "C" void kernel_launch(void* const* d_in, const int* in_sizes, int n_in,
                              void* d_out, int out_size, void* d_ws, size_t ws_size,
                              hipStream_t stream)
{
  const float* x   = (const float*)d_in[0];
  const float* w_e[4]  = {(const float*)d_in[1], (const float*)d_in[4], (const float*)d_in[7], (const float*)d_in[10]};
  const float* g_e[4]  = {(const float*)d_in[2], (const float*)d_in[5], (const float*)d_in[8], (const float*)d_in[11]};
  const float* b_e[4]  = {(const float*)d_in[3], (const float*)d_in[6], (const float*)d_in[9], (const float*)d_in[12]};
  const float* w5  = (const float*)d_in[13];
  const float* g5  = (const float*)d_in[14];
  const float* b5  = (const float*)d_in[15];
  const float* w6  = (const float*)d_in[16];
  const float* wb6 = (const float*)d_in[17];
  const float* g6  = (const float*)d_in[18];
  const float* b6  = (const float*)d_in[19];
  const float* w7  = (const float*)d_in[20];
  const float* wb7 = (const float*)d_in[21];
  const float* g7  = (const float*)d_in[22];
  const float* b7  = (const float*)d_in[23];
  const float* w8  = (const float*)d_in[24];
  const float* wb8 = (const float*)d_in[25];

  float* WS = (float*)d_ws;
  float* H    = WS;                          // 7,888,896
  float* V    = WS + 7888896;                // 4,194,304
  float* U    = V  + 4194304;                // 4,194,304
  float* YMX  = U  + 4194304;                // 4,194,304
  float* YMN  = YMX+ 4194304;                // 4,194,304
  int*   IDX  = (int*)(YMN + 4194304);       //   163,840 ints
  float* X2   = (float*)(IDX + 163840);      //     8,192
  float* SUM  = X2 + 8192;                   //       512
  float* SUMSQ= SUM + 512;                   //       512
  float* SC   = SUMSQ + 512;                 //       512
  float* SH   = SC + 512;                    //       512
  float* SUM5 = SH + 512;                    //     2,048
  float* SUMSQ5 = SUM5 + 2048;               //     2,048
  unsigned* MAXB = (unsigned*)(SUMSQ5 + 2048); //   8,192
  unsigned* MINB = MAXB + 8192;              //     8,192
  float* P    = (float*)(MINB + 8192);       //     8,192
  float* Y6   = P + 8192;                    //     8,192
  float* Z    = Y6 + 8192;                   //    16,384
  float* Y7   = Z + 16384;                   //    16,384
  float* Z7   = Y7 + 16384;                  //    16,384
  // aliases (stage-disjoint lifetimes):
  _Float16* Hf  = (_Float16*)V;              // l5 operand, after edge stages
  _Float16* Wf  = (_Float16*)U;              // l5 operand
  // knn/edge split operands live in YMN (dead until k_gather overwrites);
  // Gram G1 lives in V (dead until k_vu_mfma writes it, after k_sel reads).
  _Float16* Xhi  = (_Float16*)YMN;                 // 4 MB
  _Float16* Xlo  = Xhi + (size_t)4*2048*256;       // 4 MB
  _Float16* Wsph = Xlo + (size_t)4*2048*256;       // 0.5 MB (max 1024x256)
  _Float16* Wspl = Wsph + 1024*256;                // 0.5 MB
  float* G0 = YMX;                           // per-batch Gram (16.8 MB each)
  float* G1 = V;

  k_convert<<<96,256,0,stream>>>(x, H);

  const int Cin_[4]  = {3,64,128,256};
  const int Cpad_[4] = {32,64,128,256};
  const int O_[4]    = {64,128,256,512};
  const int ioff_[4] = {0,3,67,195};
  const int ooff_[4] = {3,67,195,451};

  for (int l=0;l<4;++l){
    const float* Xl = H + (size_t)ioff_[l]*NPTS;
    int C = Cin_[l], Cpad = Cpad_[l], O = O_[l];
    k_norms<<<32,256,0,stream>>>(Xl, C, X2, SUM);
    dim3 gxs(32, (Cpad+63)/64, 4);
    k_xsplit<<<gxs,256,0,stream>>>(Xl, C, Cpad, Xhi, Xlo);
    k_wsplit<<<(2*O*Cpad+255)/256,256,0,stream>>>(w_e[l], C, Cpad, O, Wsph, Wspl);
    dim3 ggr(16,16,2);
    k_gram<<<ggr,256,0,stream>>>(Xhi, Xlo, Cpad, 0, G0, G1);
    dim3 gsl(512,2);
    k_sel<<<gsl,256,0,stream>>>(G0, G1, X2, 0, IDX);
    k_gram<<<ggr,256,0,stream>>>(Xhi, Xlo, Cpad, 2, G0, G1);
    k_sel<<<gsl,256,0,stream>>>(G0, G1, X2, 2, IDX);
    dim3 gvm(16, (2*O)/128, 4);
    k_vu_mfma<<<gvm,256,0,stream>>>(Xhi, Xlo, Wsph, Wspl, Cpad, O, V, U);
    if (O == 64)
      k_gather<64,1><<<1024,256,0,stream>>>(V, U, IDX, YMX, YMN, SUM, SUMSQ);
    else if (O == 128)
      k_gather<128,1><<<1024,256,0,stream>>>(V, U, IDX, YMX, YMN, SUM, SUMSQ);
    else if (O == 256)
      k_gather<128,2><<<2048,256,0,stream>>>(V, U, IDX, YMX, YMN, SUM, SUMSQ);
    else
      k_gather<128,4><<<4096,256,0,stream>>>(V, U, IDX, YMX, YMN, SUM, SUMSQ);
    k_finalize<<<2,256,0,stream>>>(SUM, SUMSQ, g_e[l], b_e[l], O, 1.f/163840.f, SC, SH);
    dim3 gap(32, O/64, 4);
    k_apply<<<gap,256,0,stream>>>(YMX, YMN, SC, SH, O, H + (size_t)ooff_[l]*NPTS);
  }

  // ---- layer 5 on MFMA ----
  dim3 gtr(32,16,4);
  k_h2f16<<<gtr,256,0,stream>>>(H, Hf);
  k_w5f16<<<(2048*KPAD+255)/256,256,0,stream>>>(w5, Wf, (unsigned*)SUM5);
  dim3 g5g(16,16,4);
  k_l5mfma<<<g5g,256,0,stream>>>(Wf, Hf, SUM5, SUMSQ5, MAXB, MINB);
  k_l5_final<<<8,256,0,stream>>>(SUM5, SUMSQ5, MAXB, MINB, g5, b5, P);

  k_fc<<<512,256,0,stream>>>(w6, wb6, P, 2048, 2048, Y6);
  k_bn4<<<8,256,0,stream>>>(Y6, g6, b6, 2048, Z, 4096, 0);
  k_copy_p<<<32,256,0,stream>>>(P, Z);
  k_fc<<<1024,256,0,stream>>>(w7, wb7, Z, 4096, 4096, Y7);
  k_bn4<<<16,256,0,stream>>>(Y7, g7, b7, 4096, Z7, 4096, 0);
  k_final<<<100,256,0,stream>>>(w8, wb8, Z7, (float*)d_out);
}